// Round 5
// baseline (687.352 us; speedup 1.0000x reference)
//
#include <hip/hip_runtime.h>
#include <hip/hip_bf16.h>
#include <math.h>

#define BATCH 8
#define SQL 4096
#define SKL 4096
#define DIM 256
#define KVB 32
#define NIT (SKL / KVB)

typedef __attribute__((ext_vector_type(8))) short short8;
typedef __attribute__((ext_vector_type(4))) float f32x4;
typedef __attribute__((ext_vector_type(4))) float floatx4;

typedef __attribute__((address_space(3))) unsigned int lds_uint;
typedef __attribute__((address_space(1))) unsigned int glob_uint;

__device__ __forceinline__ void gl_lds16(const void* g, void* l) {
  __builtin_amdgcn_global_load_lds((const glob_uint*)g, (lds_uint*)l, 16, 0, 0);
}

__device__ __forceinline__ short f2bf(float f) {
  union { float f; unsigned u; } x; x.f = f;
  unsigned r = x.u + 0x7fffu + ((x.u >> 16) & 1u);
  return (short)(r >> 16);
}

// ---------- W fp32 -> bf16, once ----------
__global__ __launch_bounds__(256) void wcvt_kernel(
    const float* __restrict__ W0, const float* __restrict__ W1,
    const float* __restrict__ W2, short* __restrict__ out)
{
  const int m = blockIdx.x >> 5;
  const int i = ((blockIdx.x & 31) * 256 + threadIdx.x) * 8;
  const float* W = (m == 0) ? W0 : ((m == 1) ? W1 : W2);
  floatx4 a = *(const floatx4*)(W + i);
  floatx4 c = *(const floatx4*)(W + i + 4);
  short8 v;
  #pragma unroll
  for (int j = 0; j < 4; ++j) { v[j] = f2bf(a[j]); v[j+4] = f2bf(c[j]); }
  *(short8*)(out + (size_t)m * DIM * DIM + i) = v;
}

// ---------- projection: 32 m-rows/block; C = X.W^T + b, bf16 row-major out ----------
__global__ __launch_bounds__(256) void proj_kernel(
    const float* __restrict__ X, const short* __restrict__ Wb,
    const float* __restrict__ bias, short* __restrict__ out)
{
  const int lane = threadIdx.x & 63;
  const int wave = threadIdx.x >> 6;
  const int lr = lane & 15, hi = lane >> 4;
  const int m0 = blockIdx.x * 32;
  const int n0 = wave * 64;

  f32x4 acc0[4] = {(f32x4)0.f,(f32x4)0.f,(f32x4)0.f,(f32x4)0.f};
  f32x4 acc1[4] = {(f32x4)0.f,(f32x4)0.f,(f32x4)0.f,(f32x4)0.f};
  const float* xr0 = X + (size_t)(m0 + lr) * DIM;
  const float* xr1 = X + (size_t)(m0 + 16 + lr) * DIM;

  #pragma unroll
  for (int kk = 0; kk < 8; ++kk) {
    const int k8 = kk * 32 + hi * 8;
    floatx4 xa = *(const floatx4*)(xr0 + k8);
    floatx4 xb = *(const floatx4*)(xr0 + k8 + 4);
    floatx4 ya = *(const floatx4*)(xr1 + k8);
    floatx4 yb = *(const floatx4*)(xr1 + k8 + 4);
    short8 a0, a1;
    #pragma unroll
    for (int j = 0; j < 4; ++j) {
      a0[j] = f2bf(xa[j]); a0[j+4] = f2bf(xb[j]);
      a1[j] = f2bf(ya[j]); a1[j+4] = f2bf(yb[j]);
    }
    #pragma unroll
    for (int nb = 0; nb < 4; ++nb) {
      short8 bfr = *(const short8*)(Wb + (size_t)(n0 + nb*16 + lr) * DIM + k8);
      acc0[nb] = __builtin_amdgcn_mfma_f32_16x16x32_bf16(a0, bfr, acc0[nb], 0, 0, 0);
      acc1[nb] = __builtin_amdgcn_mfma_f32_16x16x32_bf16(a1, bfr, acc1[nb], 0, 0, 0);
    }
  }
  #pragma unroll
  for (int nb = 0; nb < 4; ++nb) {
    const int n = n0 + nb*16 + lr;
    const float bv = bias[n];
    #pragma unroll
    for (int r = 0; r < 4; ++r) {
      out[(size_t)(m0 + hi*4 + r) * DIM + n]      = f2bf(acc0[nb][r] + bv);
      out[(size_t)(m0 + 16 + hi*4 + r) * DIM + n] = f2bf(acc1[nb][r] + bv);
    }
  }
}

// ---------- V projection, output TRANSPOSED: outT[b][d][k], 32 rows/block ----------
__global__ __launch_bounds__(256) void projV_kernel(
    const float* __restrict__ X, const short* __restrict__ Wb,
    const float* __restrict__ bias, short* __restrict__ outT)
{
  __shared__ short tile[32][264];
  const int lane = threadIdx.x & 63;
  const int wave = threadIdx.x >> 6;
  const int lr = lane & 15, hi = lane >> 4;
  const int m0 = blockIdx.x * 32;
  const int n0 = wave * 64;

  f32x4 acc0[4] = {(f32x4)0.f,(f32x4)0.f,(f32x4)0.f,(f32x4)0.f};
  f32x4 acc1[4] = {(f32x4)0.f,(f32x4)0.f,(f32x4)0.f,(f32x4)0.f};
  const float* xr0 = X + (size_t)(m0 + lr) * DIM;
  const float* xr1 = X + (size_t)(m0 + 16 + lr) * DIM;

  #pragma unroll
  for (int kk = 0; kk < 8; ++kk) {
    const int k8 = kk * 32 + hi * 8;
    floatx4 xa = *(const floatx4*)(xr0 + k8);
    floatx4 xb = *(const floatx4*)(xr0 + k8 + 4);
    floatx4 ya = *(const floatx4*)(xr1 + k8);
    floatx4 yb = *(const floatx4*)(xr1 + k8 + 4);
    short8 a0, a1;
    #pragma unroll
    for (int j = 0; j < 4; ++j) {
      a0[j] = f2bf(xa[j]); a0[j+4] = f2bf(xb[j]);
      a1[j] = f2bf(ya[j]); a1[j+4] = f2bf(yb[j]);
    }
    #pragma unroll
    for (int nb = 0; nb < 4; ++nb) {
      short8 bfr = *(const short8*)(Wb + (size_t)(n0 + nb*16 + lr) * DIM + k8);
      acc0[nb] = __builtin_amdgcn_mfma_f32_16x16x32_bf16(a0, bfr, acc0[nb], 0, 0, 0);
      acc1[nb] = __builtin_amdgcn_mfma_f32_16x16x32_bf16(a1, bfr, acc1[nb], 0, 0, 0);
    }
  }
  #pragma unroll
  for (int nb = 0; nb < 4; ++nb) {
    const int n = n0 + nb*16 + lr;
    const float bv = bias[n];
    #pragma unroll
    for (int r = 0; r < 4; ++r) {
      tile[hi*4 + r][n]      = f2bf(acc0[nb][r] + bv);
      tile[16 + hi*4 + r][n] = f2bf(acc1[nb][r] + bv);
    }
  }
  __syncthreads();
  const int t = threadIdx.x;            // d index 0..255
  short8 v0, v1, v2, v3;
  #pragma unroll
  for (int k = 0; k < 8; ++k) {
    v0[k] = tile[k][t]; v1[k] = tile[k+8][t];
    v2[k] = tile[k+16][t]; v3[k] = tile[k+24][t];
  }
  const int b  = m0 >> 12;
  const int k0 = m0 & (SKL - 1);
  short* p = outT + (size_t)b * DIM * SKL + (size_t)t * SKL + k0;
  *(short8*)(p)      = v0;
  *(short8*)(p + 8)  = v1;
  *(short8*)(p + 16) = v2;
  *(short8*)(p + 24) = v3;
}

// ---------- flash attention: 4 waves/block, 32 q-rows/wave, KVB=32, dbuf, 2 blocks/CU ----------
__global__ __launch_bounds__(256, 2) void attn_kernel(
    const short* __restrict__ Qb, const short* __restrict__ Kb,
    const short* __restrict__ VtG, float* __restrict__ out)
{
  __shared__ alignas(16) short Kt[2][32][256];   // [buf][k][d], 512B rows, swz (row&7)<<4
  __shared__ alignas(16) short Vt[2][256][32];   // [buf][d][k], 64B rows, swz (d&3)<<4
  __shared__ alignas(16) short Pl[4][32][32];    // per-wave P [q][k], 64B rows, swz (q&3)<<4

  const int tid  = threadIdx.x;
  const int lane = tid & 63;
  const int wave = tid >> 6;                     // 0..3
  const int lr = lane & 15, hi = lane >> 4;

  const int b     = blockIdx.x & 7;     // batch -> XCD pinning (grid=256)
  const int qtile = blockIdx.x >> 3;    // 0..31
  const int q0w   = qtile * 128 + wave * 32;

  const short* Qp = Qb  + ((size_t)b * SQL + q0w) * DIM;
  const short* Kp = Kb  + (size_t)b * SKL * DIM;
  const short* Vp = VtG + (size_t)b * DIM * SKL;

  short8 qf0[8], qf1[8];
  #pragma unroll
  for (int kk = 0; kk < 8; ++kk) {
    qf0[kk] = *(const short8*)(Qp + (size_t)lr        * DIM + kk*32 + hi*8);
    qf1[kk] = *(const short8*)(Qp + (size_t)(16 + lr) * DIM + kk*32 + hi*8);
  }

  f32x4 o0[16], o1[16];
  #pragma unroll
  for (int i = 0; i < 16; ++i) { o0[i] = (f32x4)0.f; o1[i] = (f32x4)0.f; }
  float m0r[4] = {-3.0e38f,-3.0e38f,-3.0e38f,-3.0e38f};
  float m1r[4] = {-3.0e38f,-3.0e38f,-3.0e38f,-3.0e38f};
  float l0r[4] = {0.f,0.f,0.f,0.f};
  float l1r[4] = {0.f,0.f,0.f,0.f};

  // stage one KVB=32 tile: linear LDS dest + inverse-swizzled global src (4 waves share)
  auto stage = [&](int buf, int kv) {
    #pragma unroll
    for (int i = 0; i < 4; ++i) {              // K: 32 rows x 512B
      const int row0 = wave*8 + i*2;
      const int row  = row0 + (lane >> 5);
      const int colb = ((lane & 31) * 16) ^ ((row & 7) << 4);
      gl_lds16((const char*)(Kp + (size_t)(kv + row) * DIM) + colb, (void*)&Kt[buf][row0][0]);
    }
    #pragma unroll
    for (int i = 0; i < 4; ++i) {              // V^T: 256 rows x 64B
      const int d0 = wave*64 + i*16;
      const int d  = d0 + (lane >> 2);
      const int colb = ((lane & 3) * 16) ^ ((d & 3) << 4);
      gl_lds16((const char*)(Vp + (size_t)d * SKL + kv) + colb, (void*)&Vt[buf][d0][0]);
    }
  };

  stage(0, 0);
  __syncthreads();
  int cur = 0;

  const char* plw = (const char*)&Pl[wave][0][0];

  for (int it = 0; it < NIT; ++it) {
    if (it + 1 < NIT) stage(cur ^ 1, (it + 1) * KVB);

    // ---- QK^T: S[32q][32k]; each K-frag feeds 2 MFMAs ----
    const char* ktb = (const char*)&Kt[cur][0][0];
    f32x4 s0[2], s1[2];
    s0[0] = (f32x4)0.f; s0[1] = (f32x4)0.f; s1[0] = (f32x4)0.f; s1[1] = (f32x4)0.f;
    #pragma unroll
    for (int kk = 0; kk < 8; ++kk) {
      #pragma unroll
      for (int ks = 0; ks < 2; ++ks) {
        const int row = ks*16 + lr;
        short8 kf = *(const short8*)(ktb + row*512 + (((kk*64) + hi*16) ^ ((row & 7) << 4)));
        s0[ks] = __builtin_amdgcn_mfma_f32_16x16x32_bf16(qf0[kk], kf, s0[ks], 0, 0, 0);
        s1[ks] = __builtin_amdgcn_mfma_f32_16x16x32_bf16(qf1[kk], kf, s1[ks], 0, 0, 0);
      }
    }

    // ---- online softmax (rows hi*4+r and 16+hi*4+r; cols ks*16+lr) ----
    float mx0[4], mx1[4];
    #pragma unroll
    for (int r = 0; r < 4; ++r) {
      mx0[r] = fmaxf(s0[0][r], s0[1][r]);
      mx1[r] = fmaxf(s1[0][r], s1[1][r]);
    }
    #pragma unroll
    for (int off = 8; off >= 1; off >>= 1)
      #pragma unroll
      for (int r = 0; r < 4; ++r) {
        mx0[r] = fmaxf(mx0[r], __shfl_xor(mx0[r], off, 64));
        mx1[r] = fmaxf(mx1[r], __shfl_xor(mx1[r], off, 64));
      }

    float ps0[4], ps1[4];
    #pragma unroll
    for (int r = 0; r < 4; ++r) {
      {
        const float mn = fmaxf(m0r[r], mx0[r]);
        const float sc = __expf(m0r[r] - mn);
        m0r[r] = mn;
        const int row = hi*4 + r;
        float acc = 0.f;
        #pragma unroll
        for (int ks = 0; ks < 2; ++ks) {
          const float p = __expf(s0[ks][r] - mn);
          acc += p;
          *(short*)(plw + row*64 + ((2*(ks*16 + lr)) ^ ((row & 3) << 4))) = f2bf(p);
        }
        ps0[r] = acc;
        l0r[r] *= sc;
        #pragma unroll
        for (int dt = 0; dt < 16; ++dt) o0[dt][r] *= sc;
      }
      {
        const float mn = fmaxf(m1r[r], mx1[r]);
        const float sc = __expf(m1r[r] - mn);
        m1r[r] = mn;
        const int row = 16 + hi*4 + r;
        float acc = 0.f;
        #pragma unroll
        for (int ks = 0; ks < 2; ++ks) {
          const float p = __expf(s1[ks][r] - mn);
          acc += p;
          *(short*)(plw + row*64 + ((2*(ks*16 + lr)) ^ ((row & 3) << 4))) = f2bf(p);
        }
        ps1[r] = acc;
        l1r[r] *= sc;
        #pragma unroll
        for (int dt = 0; dt < 16; ++dt) o1[dt][r] *= sc;
      }
    }
    #pragma unroll
    for (int off = 8; off >= 1; off >>= 1)
      #pragma unroll
      for (int r = 0; r < 4; ++r) {
        ps0[r] += __shfl_xor(ps0[r], off, 64);
        ps1[r] += __shfl_xor(ps1[r], off, 64);
      }
    #pragma unroll
    for (int r = 0; r < 4; ++r) { l0r[r] += ps0[r]; l1r[r] += ps1[r]; }

    // ---- PV: O[32q][256d] += P[32q][32k] . V[32k][256d]; each V-frag feeds 2 MFMAs ----
    const char* vtb = (const char*)&Vt[cur][0][0];
    short8 pa0, pa1;
    pa0 = *(const short8*)(plw + lr*64        + ((hi*16) ^ ((lr & 3) << 4)));
    {
      const int row1 = 16 + lr;
      pa1 = *(const short8*)(plw + row1*64    + ((hi*16) ^ ((row1 & 3) << 4)));
    }
    #pragma unroll
    for (int dt = 0; dt < 16; ++dt) {
      const int d = dt*16 + lr;
      short8 vf = *(const short8*)(vtb + d*64 + ((hi*16) ^ ((d & 3) << 4)));
      o0[dt] = __builtin_amdgcn_mfma_f32_16x16x32_bf16(pa0, vf, o0[dt], 0, 0, 0);
      o1[dt] = __builtin_amdgcn_mfma_f32_16x16x32_bf16(pa1, vf, o1[dt], 0, 0, 0);
    }

    __syncthreads();
    cur ^= 1;
  }

  // ---- epilogue ----
  float* op = out + ((size_t)b * SQL + q0w) * DIM;
  #pragma unroll
  for (int r = 0; r < 4; ++r) {
    const float inv0 = 1.0f / l0r[r];
    const float inv1 = 1.0f / l1r[r];
    #pragma unroll
    for (int dt = 0; dt < 16; ++dt) {
      op[(size_t)(hi*4 + r) * DIM + dt*16 + lr]      = o0[dt][r] * inv0;
      op[(size_t)(16 + hi*4 + r) * DIM + dt*16 + lr] = o1[dt][r] * inv1;
    }
  }
}

extern "C" void kernel_launch(void* const* d_in, const int* in_sizes, int n_in,
                              void* d_out, int out_size, void* d_ws, size_t ws_size,
                              hipStream_t stream) {
  const float* query  = (const float*)d_in[0];
  const float* keys   = (const float*)d_in[1];
  const float* values = (const float*)d_in[2];
  const float* Wq = (const float*)d_in[3];
  const float* bq = (const float*)d_in[4];
  const float* Wk = (const float*)d_in[5];
  const float* bk = (const float*)d_in[6];
  const float* Wv = (const float*)d_in[7];
  const float* bv = (const float*)d_in[8];
  float* out = (float*)d_out;

  const size_t elems = (size_t)BATCH * SQL * DIM;
  short* Qb  = (short*)d_ws;
  short* Kb  = Qb + elems;
  short* VtT = Kb + elems;                          // [B][D][SK]

  const size_t wbytes = (size_t)3 * DIM * DIM * sizeof(short);
  short* Wb;
  if (ws_size >= 3 * elems * sizeof(short) + wbytes)
    Wb = VtT + elems;
  else
    Wb = (short*)((char*)d_out + (size_t)out_size * sizeof(float) - wbytes);
  short* Wqb = Wb;
  short* Wkb = Wb + DIM * DIM;
  short* Wvb = Wb + 2 * DIM * DIM;

  dim3 blk(256, 1, 1);
  wcvt_kernel <<<dim3(96, 1, 1),            blk, 0, stream>>>(Wq, Wk, Wv, Wb);
  proj_kernel <<<dim3(BATCH*SQL/32, 1, 1),  blk, 0, stream>>>(query,  Wqb, bq, Qb);
  proj_kernel <<<dim3(BATCH*SKL/32, 1, 1),  blk, 0, stream>>>(keys,   Wkb, bk, Kb);
  projV_kernel<<<dim3(BATCH*SKL/32, 1, 1),  blk, 0, stream>>>(values, Wvb, bv, VtT);
  attn_kernel <<<dim3(BATCH*SQL/128, 1, 1), blk, 0, stream>>>(Qb, Kb, VtT, out);
}

// Round 6
// 633.489 us; speedup vs baseline: 1.0850x; 1.0850x over previous
//
#include <hip/hip_runtime.h>
#include <hip/hip_bf16.h>
#include <math.h>

#define BATCH 8
#define SQL 4096
#define SKL 4096
#define DIM 256
#define KVB 32

typedef __attribute__((ext_vector_type(8))) short short8;
typedef __attribute__((ext_vector_type(4))) float f32x4;
typedef __attribute__((ext_vector_type(4))) float floatx4;

typedef __attribute__((address_space(3))) unsigned int lds_uint;
typedef __attribute__((address_space(1))) unsigned int glob_uint;

__device__ __forceinline__ void gl_lds16(const void* g, void* l) {
  __builtin_amdgcn_global_load_lds((const glob_uint*)g, (lds_uint*)l, 16, 0, 0);
}

__device__ __forceinline__ short f2bf(float f) {
  union { float f; unsigned u; } x; x.f = f;
  unsigned r = x.u + 0x7fffu + ((x.u >> 16) & 1u);
  return (short)(r >> 16);
}

// swizzles: K rows are 512B (8 slots), V^T/P rows are 64B (4 slots, fold bit2-3 of row)
__device__ __forceinline__ int swzK(int row) { return (row & 7) << 4; }
__device__ __forceinline__ int swzV(int row) { return (((row & 3) ^ ((row >> 2) & 3)) << 4); }

// ---------- W fp32 -> bf16, once ----------
__global__ __launch_bounds__(256) void wcvt_kernel(
    const float* __restrict__ W0, const float* __restrict__ W1,
    const float* __restrict__ W2, short* __restrict__ out)
{
  const int m = blockIdx.x >> 5;
  const int i = ((blockIdx.x & 31) * 256 + threadIdx.x) * 8;
  const float* W = (m == 0) ? W0 : ((m == 1) ? W1 : W2);
  floatx4 a = *(const floatx4*)(W + i);
  floatx4 c = *(const floatx4*)(W + i + 4);
  short8 v;
  #pragma unroll
  for (int j = 0; j < 4; ++j) { v[j] = f2bf(a[j]); v[j+4] = f2bf(c[j]); }
  *(short8*)(out + (size_t)m * DIM * DIM + i) = v;
}

// ---------- projection: 32 m-rows/block; C = X.W^T + b, bf16 row-major out ----------
__global__ __launch_bounds__(256) void proj_kernel(
    const float* __restrict__ X, const short* __restrict__ Wb,
    const float* __restrict__ bias, short* __restrict__ out)
{
  const int lane = threadIdx.x & 63;
  const int wave = threadIdx.x >> 6;
  const int lr = lane & 15, hi = lane >> 4;
  const int m0 = blockIdx.x * 32;
  const int n0 = wave * 64;

  f32x4 acc0[4] = {(f32x4)0.f,(f32x4)0.f,(f32x4)0.f,(f32x4)0.f};
  f32x4 acc1[4] = {(f32x4)0.f,(f32x4)0.f,(f32x4)0.f,(f32x4)0.f};
  const float* xr0 = X + (size_t)(m0 + lr) * DIM;
  const float* xr1 = X + (size_t)(m0 + 16 + lr) * DIM;

  #pragma unroll
  for (int kk = 0; kk < 8; ++kk) {
    const int k8 = kk * 32 + hi * 8;
    floatx4 xa = *(const floatx4*)(xr0 + k8);
    floatx4 xb = *(const floatx4*)(xr0 + k8 + 4);
    floatx4 ya = *(const floatx4*)(xr1 + k8);
    floatx4 yb = *(const floatx4*)(xr1 + k8 + 4);
    short8 a0, a1;
    #pragma unroll
    for (int j = 0; j < 4; ++j) {
      a0[j] = f2bf(xa[j]); a0[j+4] = f2bf(xb[j]);
      a1[j] = f2bf(ya[j]); a1[j+4] = f2bf(yb[j]);
    }
    #pragma unroll
    for (int nb = 0; nb < 4; ++nb) {
      short8 bfr = *(const short8*)(Wb + (size_t)(n0 + nb*16 + lr) * DIM + k8);
      acc0[nb] = __builtin_amdgcn_mfma_f32_16x16x32_bf16(a0, bfr, acc0[nb], 0, 0, 0);
      acc1[nb] = __builtin_amdgcn_mfma_f32_16x16x32_bf16(a1, bfr, acc1[nb], 0, 0, 0);
    }
  }
  #pragma unroll
  for (int nb = 0; nb < 4; ++nb) {
    const int n = n0 + nb*16 + lr;
    const float bv = bias[n];
    #pragma unroll
    for (int r = 0; r < 4; ++r) {
      out[(size_t)(m0 + hi*4 + r) * DIM + n]      = f2bf(acc0[nb][r] + bv);
      out[(size_t)(m0 + 16 + hi*4 + r) * DIM + n] = f2bf(acc1[nb][r] + bv);
    }
  }
}

// ---------- V projection, output TRANSPOSED: outT[b][d][k], 32 rows/block ----------
__global__ __launch_bounds__(256) void projV_kernel(
    const float* __restrict__ X, const short* __restrict__ Wb,
    const float* __restrict__ bias, short* __restrict__ outT)
{
  __shared__ short tile[32][264];
  const int lane = threadIdx.x & 63;
  const int wave = threadIdx.x >> 6;
  const int lr = lane & 15, hi = lane >> 4;
  const int m0 = blockIdx.x * 32;
  const int n0 = wave * 64;

  f32x4 acc0[4] = {(f32x4)0.f,(f32x4)0.f,(f32x4)0.f,(f32x4)0.f};
  f32x4 acc1[4] = {(f32x4)0.f,(f32x4)0.f,(f32x4)0.f,(f32x4)0.f};
  const float* xr0 = X + (size_t)(m0 + lr) * DIM;
  const float* xr1 = X + (size_t)(m0 + 16 + lr) * DIM;

  #pragma unroll
  for (int kk = 0; kk < 8; ++kk) {
    const int k8 = kk * 32 + hi * 8;
    floatx4 xa = *(const floatx4*)(xr0 + k8);
    floatx4 xb = *(const floatx4*)(xr0 + k8 + 4);
    floatx4 ya = *(const floatx4*)(xr1 + k8);
    floatx4 yb = *(const floatx4*)(xr1 + k8 + 4);
    short8 a0, a1;
    #pragma unroll
    for (int j = 0; j < 4; ++j) {
      a0[j] = f2bf(xa[j]); a0[j+4] = f2bf(xb[j]);
      a1[j] = f2bf(ya[j]); a1[j+4] = f2bf(yb[j]);
    }
    #pragma unroll
    for (int nb = 0; nb < 4; ++nb) {
      short8 bfr = *(const short8*)(Wb + (size_t)(n0 + nb*16 + lr) * DIM + k8);
      acc0[nb] = __builtin_amdgcn_mfma_f32_16x16x32_bf16(a0, bfr, acc0[nb], 0, 0, 0);
      acc1[nb] = __builtin_amdgcn_mfma_f32_16x16x32_bf16(a1, bfr, acc1[nb], 0, 0, 0);
    }
  }
  #pragma unroll
  for (int nb = 0; nb < 4; ++nb) {
    const int n = n0 + nb*16 + lr;
    const float bv = bias[n];
    #pragma unroll
    for (int r = 0; r < 4; ++r) {
      tile[hi*4 + r][n]      = f2bf(acc0[nb][r] + bv);
      tile[16 + hi*4 + r][n] = f2bf(acc1[nb][r] + bv);
    }
  }
  __syncthreads();
  const int t = threadIdx.x;
  short8 v0, v1, v2, v3;
  #pragma unroll
  for (int k = 0; k < 8; ++k) {
    v0[k] = tile[k][t]; v1[k] = tile[k+8][t];
    v2[k] = tile[k+16][t]; v3[k] = tile[k+24][t];
  }
  const int b  = m0 >> 12;
  const int k0 = m0 & (SKL - 1);
  short* p = outT + (size_t)b * DIM * SKL + (size_t)t * SKL + k0;
  *(short8*)(p)      = v0;
  *(short8*)(p + 8)  = v1;
  *(short8*)(p + 16) = v2;
  *(short8*)(p + 24) = v3;
}

// ---------- flash attention: 8 waves (512 thr), 16 q/wave, KVB=32 dbuf ----------
// KH=2: split-K halves, write unnormalized partials + (m,l).  KH=1: full KV, write out.
template<int KH>
__global__ __launch_bounds__(512, 4) void attn_kernel(
    const short* __restrict__ Qb, const short* __restrict__ Kb,
    const short* __restrict__ VtG, float* __restrict__ out,
    float* __restrict__ Opart, float2* __restrict__ ml)
{
  __shared__ alignas(16) short Kt[2][32][256];   // 32 KB
  __shared__ alignas(16) short Vt[2][256][32];   // 32 KB
  __shared__ alignas(16) short Pl[8][16][32];    // 8 KB

  const int tid  = threadIdx.x;
  const int lane = tid & 63;
  const int wave = tid >> 6;                     // 0..7
  const int lr = lane & 15, hi = lane >> 4;

  const int b     = blockIdx.x & 7;              // batch -> XCD pinning
  const int kh    = (KH == 2) ? ((blockIdx.x >> 3) & 1) : 0;
  const int qtile = blockIdx.x >> ((KH == 2) ? 4 : 3);
  const int q0w   = qtile * 128 + wave * 16;
  const int kvbase = kh * (SKL / KH);
  const int NITER  = (SKL / KH) / KVB;

  const short* Qp = Qb  + ((size_t)b * SQL + q0w) * DIM;
  const short* Kp = Kb  + (size_t)b * SKL * DIM;
  const short* Vp = VtG + (size_t)b * DIM * SKL;

  short8 qf[8];
  #pragma unroll
  for (int kk = 0; kk < 8; ++kk)
    qf[kk] = *(const short8*)(Qp + (size_t)lr * DIM + kk*32 + hi*8);

  f32x4 o[16];
  #pragma unroll
  for (int i = 0; i < 16; ++i) o[i] = (f32x4)0.f;
  float mr[4]   = {-3.0e38f,-3.0e38f,-3.0e38f,-3.0e38f};
  float lsum[4] = {0.f,0.f,0.f,0.f};

  // stage KVB=32 tile (8 waves share): linear LDS dest + inverse-swizzled global src
  auto stage = [&](int buf, int kv) {
    #pragma unroll
    for (int i = 0; i < 2; ++i) {              // K: 32 rows x 512B
      const int row0 = wave*4 + i*2;
      const int row  = row0 + (lane >> 5);
      const int colb = ((lane & 31) * 16) ^ swzK(row);
      gl_lds16((const char*)(Kp + (size_t)(kvbase + kv + row) * DIM) + colb,
               (void*)&Kt[buf][row0][0]);
    }
    #pragma unroll
    for (int i = 0; i < 2; ++i) {              // V^T: 256 rows x 64B
      const int d0 = wave*32 + i*16;
      const int d  = d0 + (lane >> 2);
      const int colb = ((lane & 3) * 16) ^ swzV(d);
      gl_lds16((const char*)(Vp + (size_t)d * SKL + kvbase + kv) + colb,
               (void*)&Vt[buf][d0][0]);
    }
  };

  stage(0, 0);
  __syncthreads();
  int cur = 0;

  const char* plw = (const char*)&Pl[wave][0][0];

  for (int it = 0; it < NITER; ++it) {
    if (it + 1 < NITER) stage(cur ^ 1, (it + 1) * KVB);

    // ---- QK^T: S[16q][32k] ----
    const char* ktb = (const char*)&Kt[cur][0][0];
    f32x4 s[2];
    s[0] = (f32x4)0.f; s[1] = (f32x4)0.f;
    __builtin_amdgcn_s_setprio(1);
    #pragma unroll
    for (int kk = 0; kk < 8; ++kk) {
      #pragma unroll
      for (int ks = 0; ks < 2; ++ks) {
        const int row = ks*16 + lr;
        short8 kf = *(const short8*)(ktb + row*512 + (((kk*64) + hi*16) ^ swzK(row)));
        s[ks] = __builtin_amdgcn_mfma_f32_16x16x32_bf16(qf[kk], kf, s[ks], 0, 0, 0);
      }
    }
    __builtin_amdgcn_s_setprio(0);

    // ---- online softmax (row = hi*4+r, col = ks*16+lr) ----
    float mx[4];
    #pragma unroll
    for (int r = 0; r < 4; ++r) mx[r] = fmaxf(s[0][r], s[1][r]);
    #pragma unroll
    for (int off = 8; off >= 1; off >>= 1)
      #pragma unroll
      for (int r = 0; r < 4; ++r)
        mx[r] = fmaxf(mx[r], __shfl_xor(mx[r], off, 64));

    float ps[4];
    #pragma unroll
    for (int r = 0; r < 4; ++r) {
      const float mn = fmaxf(mr[r], mx[r]);
      const float sc = __expf(mr[r] - mn);
      mr[r] = mn;
      const int row = hi*4 + r;
      float acc = 0.f;
      #pragma unroll
      for (int ks = 0; ks < 2; ++ks) {
        const float p = __expf(s[ks][r] - mn);
        acc += p;
        *(short*)(plw + row*64 + ((2*(ks*16 + lr)) ^ swzV(row))) = f2bf(p);
      }
      ps[r] = acc;
      lsum[r] *= sc;
      #pragma unroll
      for (int dt = 0; dt < 16; ++dt) o[dt][r] *= sc;
    }
    #pragma unroll
    for (int off = 8; off >= 1; off >>= 1)
      #pragma unroll
      for (int r = 0; r < 4; ++r)
        ps[r] += __shfl_xor(ps[r], off, 64);
    #pragma unroll
    for (int r = 0; r < 4; ++r) lsum[r] += ps[r];

    // ---- PV: O[16q][256d] += P[16q][32k] . V[32k][256d] ----
    const char* vtb = (const char*)&Vt[cur][0][0];
    short8 pa = *(const short8*)(plw + lr*64 + ((hi*16) ^ swzV(lr)));
    __builtin_amdgcn_s_setprio(1);
    #pragma unroll
    for (int dt = 0; dt < 16; ++dt) {
      const int d = dt*16 + lr;
      short8 vf = *(const short8*)(vtb + d*64 + ((hi*16) ^ swzV(d)));
      o[dt] = __builtin_amdgcn_mfma_f32_16x16x32_bf16(pa, vf, o[dt], 0, 0, 0);
    }
    __builtin_amdgcn_s_setprio(0);

    __syncthreads();
    cur ^= 1;
  }

  // ---- epilogue ----
  if (KH == 1) {
    float* op = out + ((size_t)b * SQL + q0w) * DIM;
    #pragma unroll
    for (int r = 0; r < 4; ++r) {
      const float inv = 1.0f / lsum[r];
      #pragma unroll
      for (int dt = 0; dt < 16; ++dt)
        op[(size_t)(hi*4 + r) * DIM + dt*16 + lr] = o[dt][r] * inv;
    }
  } else {
    const size_t BS = (size_t)BATCH * SQL;
    float* op = Opart + ((size_t)kh * BS + (size_t)b * SQL + q0w) * DIM;
    #pragma unroll
    for (int r = 0; r < 4; ++r) {
      #pragma unroll
      for (int dt = 0; dt < 16; ++dt)
        op[(size_t)(hi*4 + r) * DIM + dt*16 + lr] = o[dt][r];
      if (lr == 0) {
        float2 e; e.x = mr[r]; e.y = lsum[r];
        ml[kh * BS + (size_t)b * SQL + q0w + hi*4 + r] = e;
      }
    }
  }
}

// ---------- merge the two split-K halves ----------
__global__ __launch_bounds__(256) void merge_kernel(
    const float* __restrict__ Opart, const float2* __restrict__ ml,
    float* __restrict__ out)
{
  const size_t BS = (size_t)BATCH * SQL;
  const int t  = threadIdx.x;
  const size_t gq = (size_t)blockIdx.x * 4 + (t >> 6);
  const int dl = (t & 63) * 4;
  float2 e0 = ml[gq], e1 = ml[BS + gq];
  const float M  = fmaxf(e0.x, e1.x);
  const float w0 = __expf(e0.x - M);
  const float w1 = __expf(e1.x - M);
  const float inv = 1.0f / (e0.y * w0 + e1.y * w1);
  f32x4 a = *(const f32x4*)(Opart + gq * DIM + dl);
  f32x4 c = *(const f32x4*)(Opart + (BS + gq) * DIM + dl);
  f32x4 r;
  #pragma unroll
  for (int j = 0; j < 4; ++j) r[j] = (a[j] * w0 + c[j] * w1) * inv;
  *(f32x4*)(out + gq * DIM + dl) = r;
}

extern "C" void kernel_launch(void* const* d_in, const int* in_sizes, int n_in,
                              void* d_out, int out_size, void* d_ws, size_t ws_size,
                              hipStream_t stream) {
  const float* query  = (const float*)d_in[0];
  const float* keys   = (const float*)d_in[1];
  const float* values = (const float*)d_in[2];
  const float* Wq = (const float*)d_in[3];
  const float* bq = (const float*)d_in[4];
  const float* Wk = (const float*)d_in[5];
  const float* bk = (const float*)d_in[6];
  const float* Wv = (const float*)d_in[7];
  const float* bv = (const float*)d_in[8];
  float* out = (float*)d_out;

  const size_t elems = (size_t)BATCH * SQL * DIM;          // 8.39M
  const size_t BS    = (size_t)BATCH * SQL;                // 32768
  short* Qb  = (short*)d_ws;
  short* Kb  = Qb + elems;
  short* VtT = Kb + elems;

  const size_t wbytes    = (size_t)3 * DIM * DIM * sizeof(short);
  const size_t need_base = 3 * elems * sizeof(short) + wbytes;
  const size_t need_split = need_base + 2 * elems * sizeof(float) + 2 * BS * sizeof(float2);

  short* Wb;
  bool wb_in_ws = (ws_size >= need_base);
  if (wb_in_ws) Wb = VtT + elems;
  else          Wb = (short*)((char*)d_out + (size_t)out_size * sizeof(float) - wbytes);
  short* Wqb = Wb;
  short* Wkb = Wb + DIM * DIM;
  short* Wvb = Wb + 2 * DIM * DIM;

  dim3 blk(256, 1, 1);
  dim3 blk512(512, 1, 1);
  wcvt_kernel <<<dim3(96, 1, 1),           blk, 0, stream>>>(Wq, Wk, Wv, Wb);
  proj_kernel <<<dim3(BATCH*SQL/32, 1, 1), blk, 0, stream>>>(query,  Wqb, bq, Qb);
  proj_kernel <<<dim3(BATCH*SKL/32, 1, 1), blk, 0, stream>>>(keys,   Wkb, bk, Kb);
  projV_kernel<<<dim3(BATCH*SKL/32, 1, 1), blk, 0, stream>>>(values, Wvb, bv, VtT);

  if (ws_size >= need_split) {
    float*  Opart = (float*)((char*)d_ws + need_base);
    float2* ml    = (float2*)(Opart + 2 * elems);
    attn_kernel<2><<<dim3(512, 1, 1), blk512, 0, stream>>>(Qb, Kb, VtT, out, Opart, ml);
    merge_kernel  <<<dim3(BS/4, 1, 1), blk,    0, stream>>>(Opart, ml, out);
  } else {
    attn_kernel<1><<<dim3(256, 1, 1), blk512, 0, stream>>>(Qb, Kb, VtT, out, nullptr, nullptr);
  }
}

// Round 7
// 435.745 us; speedup vs baseline: 1.5774x; 1.4538x over previous
//
#include <hip/hip_runtime.h>
#include <hip/hip_bf16.h>
#include <math.h>

#define BATCH 8
#define SQL 4096
#define SKL 4096
#define DIM 256
#define KVB 32

typedef __attribute__((ext_vector_type(8))) short short8;
typedef __attribute__((ext_vector_type(4))) float f32x4;
typedef __attribute__((ext_vector_type(4))) float floatx4;

typedef __attribute__((address_space(3))) unsigned int lds_uint;
typedef __attribute__((address_space(1))) unsigned int glob_uint;

__device__ __forceinline__ void gl_lds16(const void* g, void* l) {
  __builtin_amdgcn_global_load_lds((const glob_uint*)g, (lds_uint*)l, 16, 0, 0);
}

__device__ __forceinline__ short f2bf(float f) {
  union { float f; unsigned u; } x; x.f = f;
  unsigned r = x.u + 0x7fffu + ((x.u >> 16) & 1u);
  return (short)(r >> 16);
}

// swizzles: K rows are 512B (8 slots), V^T/P rows are 64B (4 slots, fold bit2-3 of row)
__device__ __forceinline__ int swzK(int row) { return (row & 7) << 4; }
__device__ __forceinline__ int swzV(int row) { return (((row & 3) ^ ((row >> 2) & 3)) << 4); }

// ---------- W fp32 -> bf16, once ----------
__global__ __launch_bounds__(256) void wcvt_kernel(
    const float* __restrict__ W0, const float* __restrict__ W1,
    const float* __restrict__ W2, short* __restrict__ out)
{
  const int m = blockIdx.x >> 5;
  const int i = ((blockIdx.x & 31) * 256 + threadIdx.x) * 8;
  const float* W = (m == 0) ? W0 : ((m == 1) ? W1 : W2);
  floatx4 a = *(const floatx4*)(W + i);
  floatx4 c = *(const floatx4*)(W + i + 4);
  short8 v;
  #pragma unroll
  for (int j = 0; j < 4; ++j) { v[j] = f2bf(a[j]); v[j+4] = f2bf(c[j]); }
  *(short8*)(out + (size_t)m * DIM * DIM + i) = v;
}

// ---------- projection: 32 m-rows/block; C = X.W^T + b, bf16 row-major out ----------
__global__ __launch_bounds__(256) void proj_kernel(
    const float* __restrict__ X, const short* __restrict__ Wb,
    const float* __restrict__ bias, short* __restrict__ out)
{
  const int lane = threadIdx.x & 63;
  const int wave = threadIdx.x >> 6;
  const int lr = lane & 15, hi = lane >> 4;
  const int m0 = blockIdx.x * 32;
  const int n0 = wave * 64;

  f32x4 acc0[4] = {(f32x4)0.f,(f32x4)0.f,(f32x4)0.f,(f32x4)0.f};
  f32x4 acc1[4] = {(f32x4)0.f,(f32x4)0.f,(f32x4)0.f,(f32x4)0.f};
  const float* xr0 = X + (size_t)(m0 + lr) * DIM;
  const float* xr1 = X + (size_t)(m0 + 16 + lr) * DIM;

  #pragma unroll
  for (int kk = 0; kk < 8; ++kk) {
    const int k8 = kk * 32 + hi * 8;
    floatx4 xa = *(const floatx4*)(xr0 + k8);
    floatx4 xb = *(const floatx4*)(xr0 + k8 + 4);
    floatx4 ya = *(const floatx4*)(xr1 + k8);
    floatx4 yb = *(const floatx4*)(xr1 + k8 + 4);
    short8 a0, a1;
    #pragma unroll
    for (int j = 0; j < 4; ++j) {
      a0[j] = f2bf(xa[j]); a0[j+4] = f2bf(xb[j]);
      a1[j] = f2bf(ya[j]); a1[j+4] = f2bf(yb[j]);
    }
    #pragma unroll
    for (int nb = 0; nb < 4; ++nb) {
      short8 bfr = *(const short8*)(Wb + (size_t)(n0 + nb*16 + lr) * DIM + k8);
      acc0[nb] = __builtin_amdgcn_mfma_f32_16x16x32_bf16(a0, bfr, acc0[nb], 0, 0, 0);
      acc1[nb] = __builtin_amdgcn_mfma_f32_16x16x32_bf16(a1, bfr, acc1[nb], 0, 0, 0);
    }
  }
  #pragma unroll
  for (int nb = 0; nb < 4; ++nb) {
    const int n = n0 + nb*16 + lr;
    const float bv = bias[n];
    #pragma unroll
    for (int r = 0; r < 4; ++r) {
      out[(size_t)(m0 + hi*4 + r) * DIM + n]      = f2bf(acc0[nb][r] + bv);
      out[(size_t)(m0 + 16 + hi*4 + r) * DIM + n] = f2bf(acc1[nb][r] + bv);
    }
  }
}

// ---------- V projection, output TRANSPOSED: outT[b][d][k], 32 rows/block ----------
__global__ __launch_bounds__(256) void projV_kernel(
    const float* __restrict__ X, const short* __restrict__ Wb,
    const float* __restrict__ bias, short* __restrict__ outT)
{
  __shared__ short tile[32][264];
  const int lane = threadIdx.x & 63;
  const int wave = threadIdx.x >> 6;
  const int lr = lane & 15, hi = lane >> 4;
  const int m0 = blockIdx.x * 32;
  const int n0 = wave * 64;

  f32x4 acc0[4] = {(f32x4)0.f,(f32x4)0.f,(f32x4)0.f,(f32x4)0.f};
  f32x4 acc1[4] = {(f32x4)0.f,(f32x4)0.f,(f32x4)0.f,(f32x4)0.f};
  const float* xr0 = X + (size_t)(m0 + lr) * DIM;
  const float* xr1 = X + (size_t)(m0 + 16 + lr) * DIM;

  #pragma unroll
  for (int kk = 0; kk < 8; ++kk) {
    const int k8 = kk * 32 + hi * 8;
    floatx4 xa = *(const floatx4*)(xr0 + k8);
    floatx4 xb = *(const floatx4*)(xr0 + k8 + 4);
    floatx4 ya = *(const floatx4*)(xr1 + k8);
    floatx4 yb = *(const floatx4*)(xr1 + k8 + 4);
    short8 a0, a1;
    #pragma unroll
    for (int j = 0; j < 4; ++j) {
      a0[j] = f2bf(xa[j]); a0[j+4] = f2bf(xb[j]);
      a1[j] = f2bf(ya[j]); a1[j+4] = f2bf(yb[j]);
    }
    #pragma unroll
    for (int nb = 0; nb < 4; ++nb) {
      short8 bfr = *(const short8*)(Wb + (size_t)(n0 + nb*16 + lr) * DIM + k8);
      acc0[nb] = __builtin_amdgcn_mfma_f32_16x16x32_bf16(a0, bfr, acc0[nb], 0, 0, 0);
      acc1[nb] = __builtin_amdgcn_mfma_f32_16x16x32_bf16(a1, bfr, acc1[nb], 0, 0, 0);
    }
  }
  #pragma unroll
  for (int nb = 0; nb < 4; ++nb) {
    const int n = n0 + nb*16 + lr;
    const float bv = bias[n];
    #pragma unroll
    for (int r = 0; r < 4; ++r) {
      tile[hi*4 + r][n]      = f2bf(acc0[nb][r] + bv);
      tile[16 + hi*4 + r][n] = f2bf(acc1[nb][r] + bv);
    }
  }
  __syncthreads();
  const int t = threadIdx.x;
  short8 v0, v1, v2, v3;
  #pragma unroll
  for (int k = 0; k < 8; ++k) {
    v0[k] = tile[k][t]; v1[k] = tile[k+8][t];
    v2[k] = tile[k+16][t]; v3[k] = tile[k+24][t];
  }
  const int b  = m0 >> 12;
  const int k0 = m0 & (SKL - 1);
  short* p = outT + (size_t)b * DIM * SKL + (size_t)t * SKL + k0;
  *(short8*)(p)      = v0;
  *(short8*)(p + 8)  = v1;
  *(short8*)(p + 16) = v2;
  *(short8*)(p + 24) = v3;
}

// ---------- flash attention: 8 waves (512 thr), 16 q/wave, KVB=32 dbuf ----------
// KH=2: split-K halves, write unnormalized partials + (m,l).  KH=1: full KV, write out.
template<int KH>
__global__ __launch_bounds__(512, 2) void attn_kernel(
    const short* __restrict__ Qb, const short* __restrict__ Kb,
    const short* __restrict__ VtG, float* __restrict__ out,
    float* __restrict__ Opart, float2* __restrict__ ml)
{
  __shared__ alignas(16) short Kt[2][32][256];   // 32 KB
  __shared__ alignas(16) short Vt[2][256][32];   // 32 KB
  __shared__ alignas(16) short Pl[8][16][32];    // 8 KB

  const int tid  = threadIdx.x;
  const int lane = tid & 63;
  const int wave = tid >> 6;                     // 0..7
  const int lr = lane & 15, hi = lane >> 4;

  const int b     = blockIdx.x & 7;              // batch -> XCD pinning
  const int kh    = (KH == 2) ? ((blockIdx.x >> 3) & 1) : 0;
  const int qtile = blockIdx.x >> ((KH == 2) ? 4 : 3);
  const int q0w   = qtile * 128 + wave * 16;
  const int kvbase = kh * (SKL / KH);
  const int NITER  = (SKL / KH) / KVB;

  const short* Qp = Qb  + ((size_t)b * SQL + q0w) * DIM;
  const short* Kp = Kb  + (size_t)b * SKL * DIM;
  const short* Vp = VtG + (size_t)b * DIM * SKL;

  short8 qf[8];
  #pragma unroll
  for (int kk = 0; kk < 8; ++kk)
    qf[kk] = *(const short8*)(Qp + (size_t)lr * DIM + kk*32 + hi*8);

  f32x4 o[16];
  #pragma unroll
  for (int i = 0; i < 16; ++i) o[i] = (f32x4)0.f;
  float mr[4]   = {-3.0e38f,-3.0e38f,-3.0e38f,-3.0e38f};
  float lsum[4] = {0.f,0.f,0.f,0.f};

  // stage KVB=32 tile (8 waves share): linear LDS dest + inverse-swizzled global src
  auto stage = [&](int buf, int kv) {
    #pragma unroll
    for (int i = 0; i < 2; ++i) {              // K: 32 rows x 512B
      const int row0 = wave*4 + i*2;
      const int row  = row0 + (lane >> 5);
      const int colb = ((lane & 31) * 16) ^ swzK(row);
      gl_lds16((const char*)(Kp + (size_t)(kvbase + kv + row) * DIM) + colb,
               (void*)&Kt[buf][row0][0]);
    }
    #pragma unroll
    for (int i = 0; i < 2; ++i) {              // V^T: 256 rows x 64B
      const int d0 = wave*32 + i*16;
      const int d  = d0 + (lane >> 2);
      const int colb = ((lane & 3) * 16) ^ swzV(d);
      gl_lds16((const char*)(Vp + (size_t)d * SKL + kvbase + kv) + colb,
               (void*)&Vt[buf][d0][0]);
    }
  };

  stage(0, 0);
  __syncthreads();
  int cur = 0;

  const char* plw = (const char*)&Pl[wave][0][0];

  for (int it = 0; it < NITER; ++it) {
    if (it + 1 < NITER) stage(cur ^ 1, (it + 1) * KVB);

    // ---- QK^T: S[16q][32k] ----
    const char* ktb = (const char*)&Kt[cur][0][0];
    f32x4 s[2];
    s[0] = (f32x4)0.f; s[1] = (f32x4)0.f;
    __builtin_amdgcn_s_setprio(1);
    #pragma unroll
    for (int kk = 0; kk < 8; ++kk) {
      #pragma unroll
      for (int ks = 0; ks < 2; ++ks) {
        const int row = ks*16 + lr;
        short8 kf = *(const short8*)(ktb + row*512 + (((kk*64) + hi*16) ^ swzK(row)));
        s[ks] = __builtin_amdgcn_mfma_f32_16x16x32_bf16(qf[kk], kf, s[ks], 0, 0, 0);
      }
    }
    __builtin_amdgcn_s_setprio(0);

    // ---- online softmax (row = hi*4+r, col = ks*16+lr) ----
    float mx[4];
    #pragma unroll
    for (int r = 0; r < 4; ++r) mx[r] = fmaxf(s[0][r], s[1][r]);
    #pragma unroll
    for (int off = 8; off >= 1; off >>= 1)
      #pragma unroll
      for (int r = 0; r < 4; ++r)
        mx[r] = fmaxf(mx[r], __shfl_xor(mx[r], off, 64));

    float ps[4];
    #pragma unroll
    for (int r = 0; r < 4; ++r) {
      const float mn = fmaxf(mr[r], mx[r]);
      const float sc = __expf(mr[r] - mn);
      mr[r] = mn;
      const int row = hi*4 + r;
      float acc = 0.f;
      #pragma unroll
      for (int ks = 0; ks < 2; ++ks) {
        const float p = __expf(s[ks][r] - mn);
        acc += p;
        *(short*)(plw + row*64 + ((2*(ks*16 + lr)) ^ swzV(row))) = f2bf(p);
      }
      ps[r] = acc;
      lsum[r] *= sc;
      #pragma unroll
      for (int dt = 0; dt < 16; ++dt) o[dt][r] *= sc;
    }
    #pragma unroll
    for (int off = 8; off >= 1; off >>= 1)
      #pragma unroll
      for (int r = 0; r < 4; ++r)
        ps[r] += __shfl_xor(ps[r], off, 64);
    #pragma unroll
    for (int r = 0; r < 4; ++r) lsum[r] += ps[r];

    // ---- PV: O[16q][256d] += P[16q][32k] . V[32k][256d] ----
    const char* vtb = (const char*)&Vt[cur][0][0];
    short8 pa = *(const short8*)(plw + lr*64 + ((hi*16) ^ swzV(lr)));
    __builtin_amdgcn_s_setprio(1);
    #pragma unroll
    for (int dt = 0; dt < 16; ++dt) {
      const int d = dt*16 + lr;
      short8 vf = *(const short8*)(vtb + d*64 + ((hi*16) ^ swzV(d)));
      o[dt] = __builtin_amdgcn_mfma_f32_16x16x32_bf16(pa, vf, o[dt], 0, 0, 0);
    }
    __builtin_amdgcn_s_setprio(0);

    __syncthreads();
    cur ^= 1;
  }

  // ---- epilogue ----
  if (KH == 1) {
    float* op = out + ((size_t)b * SQL + q0w) * DIM;
    #pragma unroll
    for (int r = 0; r < 4; ++r) {
      const float inv = 1.0f / lsum[r];
      #pragma unroll
      for (int dt = 0; dt < 16; ++dt)
        op[(size_t)(hi*4 + r) * DIM + dt*16 + lr] = o[dt][r] * inv;
    }
  } else {
    const size_t BS = (size_t)BATCH * SQL;
    float* op = Opart + ((size_t)kh * BS + (size_t)b * SQL + q0w) * DIM;
    #pragma unroll
    for (int r = 0; r < 4; ++r) {
      #pragma unroll
      for (int dt = 0; dt < 16; ++dt)
        op[(size_t)(hi*4 + r) * DIM + dt*16 + lr] = o[dt][r];
      if (lr == 0) {
        float2 e; e.x = mr[r]; e.y = lsum[r];
        ml[kh * BS + (size_t)b * SQL + q0w + hi*4 + r] = e;
      }
    }
  }
}

// ---------- merge the two split-K halves ----------
__global__ __launch_bounds__(256) void merge_kernel(
    const float* __restrict__ Opart, const float2* __restrict__ ml,
    float* __restrict__ out)
{
  const size_t BS = (size_t)BATCH * SQL;
  const int t  = threadIdx.x;
  const size_t gq = (size_t)blockIdx.x * 4 + (t >> 6);
  const int dl = (t & 63) * 4;
  float2 e0 = ml[gq], e1 = ml[BS + gq];
  const float M  = fmaxf(e0.x, e1.x);
  const float w0 = __expf(e0.x - M);
  const float w1 = __expf(e1.x - M);
  const float inv = 1.0f / (e0.y * w0 + e1.y * w1);
  f32x4 a = *(const f32x4*)(Opart + gq * DIM + dl);
  f32x4 c = *(const f32x4*)(Opart + (BS + gq) * DIM + dl);
  f32x4 r;
  #pragma unroll
  for (int j = 0; j < 4; ++j) r[j] = (a[j] * w0 + c[j] * w1) * inv;
  *(f32x4*)(out + gq * DIM + dl) = r;
}

extern "C" void kernel_launch(void* const* d_in, const int* in_sizes, int n_in,
                              void* d_out, int out_size, void* d_ws, size_t ws_size,
                              hipStream_t stream) {
  const float* query  = (const float*)d_in[0];
  const float* keys   = (const float*)d_in[1];
  const float* values = (const float*)d_in[2];
  const float* Wq = (const float*)d_in[3];
  const float* bq = (const float*)d_in[4];
  const float* Wk = (const float*)d_in[5];
  const float* bk = (const float*)d_in[6];
  const float* Wv = (const float*)d_in[7];
  const float* bv = (const float*)d_in[8];
  float* out = (float*)d_out;

  const size_t elems = (size_t)BATCH * SQL * DIM;          // 8.39M
  const size_t BS    = (size_t)BATCH * SQL;                // 32768
  short* Qb  = (short*)d_ws;
  short* Kb  = Qb + elems;
  short* VtT = Kb + elems;

  const size_t wbytes    = (size_t)3 * DIM * DIM * sizeof(short);
  const size_t need_base = 3 * elems * sizeof(short) + wbytes;
  const size_t need_split = need_base + 2 * elems * sizeof(float) + 2 * BS * sizeof(float2);

  short* Wb;
  bool wb_in_ws = (ws_size >= need_base);
  if (wb_in_ws) Wb = VtT + elems;
  else          Wb = (short*)((char*)d_out + (size_t)out_size * sizeof(float) - wbytes);
  short* Wqb = Wb;
  short* Wkb = Wb + DIM * DIM;
  short* Wvb = Wb + 2 * DIM * DIM;

  dim3 blk(256, 1, 1);
  dim3 blk512(512, 1, 1);
  wcvt_kernel <<<dim3(96, 1, 1),           blk, 0, stream>>>(Wq, Wk, Wv, Wb);
  proj_kernel <<<dim3(BATCH*SQL/32, 1, 1), blk, 0, stream>>>(query,  Wqb, bq, Qb);
  proj_kernel <<<dim3(BATCH*SKL/32, 1, 1), blk, 0, stream>>>(keys,   Wkb, bk, Kb);
  projV_kernel<<<dim3(BATCH*SKL/32, 1, 1), blk, 0, stream>>>(values, Wvb, bv, VtT);

  if (ws_size >= need_split) {
    float*  Opart = (float*)((char*)d_ws + need_base);
    float2* ml    = (float2*)(Opart + 2 * elems);
    attn_kernel<2><<<dim3(512, 1, 1), blk512, 0, stream>>>(Qb, Kb, VtT, out, Opart, ml);
    merge_kernel  <<<dim3(BS/4, 1, 1), blk,    0, stream>>>(Opart, ml, out);
  } else {
    attn_kernel<1><<<dim3(256, 1, 1), blk512, 0, stream>>>(Qb, Kb, VtT, out, nullptr, nullptr);
  }
}

// Round 9
// 390.217 us; speedup vs baseline: 1.7615x; 1.1167x over previous
//
#include <hip/hip_runtime.h>
#include <hip/hip_bf16.h>
#include <math.h>

#define BATCH 8
#define SQL 4096
#define SKL 4096
#define DIM 256
#define KVB 32

typedef __attribute__((ext_vector_type(8))) short short8;
typedef __attribute__((ext_vector_type(4))) float f32x4;
typedef __attribute__((ext_vector_type(4))) float floatx4;

typedef __attribute__((address_space(3))) unsigned int lds_uint;
typedef __attribute__((address_space(1))) unsigned int glob_uint;

__device__ __forceinline__ void gl_lds16(const void* g, void* l) {
  __builtin_amdgcn_global_load_lds((const glob_uint*)g, (lds_uint*)l, 16, 0, 0);
}

__device__ __forceinline__ short f2bf(float f) {
  union { float f; unsigned u; } x; x.f = f;
  unsigned r = x.u + 0x7fffu + ((x.u >> 16) & 1u);
  return (short)(r >> 16);
}

// swizzles (bank-derived, ~2 lanes/bank = free):
//  K rows 512B: slot ^= row&7
//  V^T/P rows 64B (4 slots): slot ^= (row>>1)&3 -> start_bank = 16*(row&1)+4*slot
__device__ __forceinline__ int swzK(int row) { return (row & 7) << 4; }
__device__ __forceinline__ int swzV(int row) { return ((row >> 1) & 3) << 4; }

// ---------- W fp32 -> bf16, once ----------
__global__ __launch_bounds__(256) void wcvt_kernel(
    const float* __restrict__ W0, const float* __restrict__ W1,
    const float* __restrict__ W2, short* __restrict__ out)
{
  const int m = blockIdx.x >> 5;
  const int i = ((blockIdx.x & 31) * 256 + threadIdx.x) * 8;
  const float* W = (m == 0) ? W0 : ((m == 1) ? W1 : W2);
  floatx4 a = *(const floatx4*)(W + i);
  floatx4 c = *(const floatx4*)(W + i + 4);
  short8 v;
  #pragma unroll
  for (int j = 0; j < 4; ++j) { v[j] = f2bf(a[j]); v[j+4] = f2bf(c[j]); }
  *(short8*)(out + (size_t)m * DIM * DIM + i) = v;
}

// ---------- projection: 32 m-rows/block; C = X.W^T + b, bf16 row-major out ----------
__global__ __launch_bounds__(256) void proj_kernel(
    const float* __restrict__ X, const short* __restrict__ Wb,
    const float* __restrict__ bias, short* __restrict__ out)
{
  const int lane = threadIdx.x & 63;
  const int wave = threadIdx.x >> 6;
  const int lr = lane & 15, hi = lane >> 4;
  const int m0 = blockIdx.x * 32;
  const int n0 = wave * 64;

  f32x4 acc0[4] = {(f32x4)0.f,(f32x4)0.f,(f32x4)0.f,(f32x4)0.f};
  f32x4 acc1[4] = {(f32x4)0.f,(f32x4)0.f,(f32x4)0.f,(f32x4)0.f};
  const float* xr0 = X + (size_t)(m0 + lr) * DIM;
  const float* xr1 = X + (size_t)(m0 + 16 + lr) * DIM;

  #pragma unroll
  for (int kk = 0; kk < 8; ++kk) {
    const int k8 = kk * 32 + hi * 8;
    floatx4 xa = *(const floatx4*)(xr0 + k8);
    floatx4 xb = *(const floatx4*)(xr0 + k8 + 4);
    floatx4 ya = *(const floatx4*)(xr1 + k8);
    floatx4 yb = *(const floatx4*)(xr1 + k8 + 4);
    short8 a0, a1;
    #pragma unroll
    for (int j = 0; j < 4; ++j) {
      a0[j] = f2bf(xa[j]); a0[j+4] = f2bf(xb[j]);
      a1[j] = f2bf(ya[j]); a1[j+4] = f2bf(yb[j]);
    }
    #pragma unroll
    for (int nb = 0; nb < 4; ++nb) {
      short8 bfr = *(const short8*)(Wb + (size_t)(n0 + nb*16 + lr) * DIM + k8);
      acc0[nb] = __builtin_amdgcn_mfma_f32_16x16x32_bf16(a0, bfr, acc0[nb], 0, 0, 0);
      acc1[nb] = __builtin_amdgcn_mfma_f32_16x16x32_bf16(a1, bfr, acc1[nb], 0, 0, 0);
    }
  }
  #pragma unroll
  for (int nb = 0; nb < 4; ++nb) {
    const int n = n0 + nb*16 + lr;
    const float bv = bias[n];
    #pragma unroll
    for (int r = 0; r < 4; ++r) {
      out[(size_t)(m0 + hi*4 + r) * DIM + n]      = f2bf(acc0[nb][r] + bv);
      out[(size_t)(m0 + 16 + hi*4 + r) * DIM + n] = f2bf(acc1[nb][r] + bv);
    }
  }
}

// ---------- V projection, output TRANSPOSED: outT[b][d][k], 32 rows/block ----------
__global__ __launch_bounds__(256) void projV_kernel(
    const float* __restrict__ X, const short* __restrict__ Wb,
    const float* __restrict__ bias, short* __restrict__ outT)
{
  __shared__ short tile[32][264];
  const int lane = threadIdx.x & 63;
  const int wave = threadIdx.x >> 6;
  const int lr = lane & 15, hi = lane >> 4;
  const int m0 = blockIdx.x * 32;
  const int n0 = wave * 64;

  f32x4 acc0[4] = {(f32x4)0.f,(f32x4)0.f,(f32x4)0.f,(f32x4)0.f};
  f32x4 acc1[4] = {(f32x4)0.f,(f32x4)0.f,(f32x4)0.f,(f32x4)0.f};
  const float* xr0 = X + (size_t)(m0 + lr) * DIM;
  const float* xr1 = X + (size_t)(m0 + 16 + lr) * DIM;

  #pragma unroll
  for (int kk = 0; kk < 8; ++kk) {
    const int k8 = kk * 32 + hi * 8;
    floatx4 xa = *(const floatx4*)(xr0 + k8);
    floatx4 xb = *(const floatx4*)(xr0 + k8 + 4);
    floatx4 ya = *(const floatx4*)(xr1 + k8);
    floatx4 yb = *(const floatx4*)(xr1 + k8 + 4);
    short8 a0, a1;
    #pragma unroll
    for (int j = 0; j < 4; ++j) {
      a0[j] = f2bf(xa[j]); a0[j+4] = f2bf(xb[j]);
      a1[j] = f2bf(ya[j]); a1[j+4] = f2bf(yb[j]);
    }
    #pragma unroll
    for (int nb = 0; nb < 4; ++nb) {
      short8 bfr = *(const short8*)(Wb + (size_t)(n0 + nb*16 + lr) * DIM + k8);
      acc0[nb] = __builtin_amdgcn_mfma_f32_16x16x32_bf16(a0, bfr, acc0[nb], 0, 0, 0);
      acc1[nb] = __builtin_amdgcn_mfma_f32_16x16x32_bf16(a1, bfr, acc1[nb], 0, 0, 0);
    }
  }
  #pragma unroll
  for (int nb = 0; nb < 4; ++nb) {
    const int n = n0 + nb*16 + lr;
    const float bv = bias[n];
    #pragma unroll
    for (int r = 0; r < 4; ++r) {
      tile[hi*4 + r][n]      = f2bf(acc0[nb][r] + bv);
      tile[16 + hi*4 + r][n] = f2bf(acc1[nb][r] + bv);
    }
  }
  __syncthreads();
  const int t = threadIdx.x;
  short8 v0, v1, v2, v3;
  #pragma unroll
  for (int k = 0; k < 8; ++k) {
    v0[k] = tile[k][t]; v1[k] = tile[k+8][t];
    v2[k] = tile[k+16][t]; v3[k] = tile[k+24][t];
  }
  const int b  = m0 >> 12;
  const int k0 = m0 & (SKL - 1);
  short* p = outT + (size_t)b * DIM * SKL + (size_t)t * SKL + k0;
  *(short8*)(p)      = v0;
  *(short8*)(p + 8)  = v1;
  *(short8*)(p + 16) = v2;
  *(short8*)(p + 24) = v3;
}

// ---------- flash attention: 8 waves (512 thr), 16 q/wave, KVB=32 dbuf, split-K ----------
// KH=2: halves write unnormalized partials + (m,l).  KH=1: full KV, write out.
template<int KH>
__global__ __launch_bounds__(512, 2) void attn_kernel(
    const short* __restrict__ Qb, const short* __restrict__ Kb,
    const short* __restrict__ VtG, float* __restrict__ out,
    float* __restrict__ Opart, float2* __restrict__ ml)
{
  __shared__ alignas(16) short Kt[2][32][256];   // 32 KB
  __shared__ alignas(16) short Vt[2][256][32];   // 32 KB
  __shared__ alignas(16) short Pl[8][16][32];    // 8 KB

  const int tid  = threadIdx.x;
  const int lane = tid & 63;
  const int wave = tid >> 6;                     // 0..7
  const int lr = lane & 15, hi = lane >> 4;

  const int b     = blockIdx.x & 7;              // batch -> XCD pinning
  const int kh    = (KH == 2) ? ((blockIdx.x >> 3) & 1) : 0;
  const int qtile = blockIdx.x >> ((KH == 2) ? 4 : 3);
  const int q0w   = qtile * 128 + wave * 16;
  const int kvbase = kh * (SKL / KH);
  const int NITER  = (SKL / KH) / KVB;

  const short* Qp = Qb  + ((size_t)b * SQL + q0w) * DIM;
  const short* Kp = Kb  + (size_t)b * SKL * DIM;
  const short* Vp = VtG + (size_t)b * DIM * SKL;

  short8 qf[8];
  #pragma unroll
  for (int kk = 0; kk < 8; ++kk)
    qf[kk] = *(const short8*)(Qp + (size_t)lr * DIM + kk*32 + hi*8);

  f32x4 o[16];
  #pragma unroll
  for (int i = 0; i < 16; ++i) o[i] = (f32x4)0.f;
  float mr[4]   = {-3.0e38f,-3.0e38f,-3.0e38f,-3.0e38f};
  float lacc[4] = {0.f,0.f,0.f,0.f};   // per-lane partial row-sum in current-m frame

  auto stage = [&](int buf, int kv) {
    #pragma unroll
    for (int i = 0; i < 2; ++i) {              // K: 32 rows x 512B
      const int row0 = wave*4 + i*2;
      const int row  = row0 + (lane >> 5);
      const int colb = ((lane & 31) * 16) ^ swzK(row);
      gl_lds16((const char*)(Kp + (size_t)(kvbase + kv + row) * DIM) + colb,
               (void*)&Kt[buf][row0][0]);
    }
    #pragma unroll
    for (int i = 0; i < 2; ++i) {              // V^T: 256 rows x 64B
      const int d0 = wave*32 + i*16;
      const int d  = d0 + (lane >> 2);
      const int colb = ((lane & 3) * 16) ^ swzV(d);
      gl_lds16((const char*)(Vp + (size_t)d * SKL + kvbase + kv) + colb,
               (void*)&Vt[buf][d0][0]);
    }
  };

  stage(0, 0);
  __syncthreads();
  int cur = 0;

  const char* plw = (const char*)&Pl[wave][0][0];

  for (int it = 0; it < NITER; ++it) {
    if (it + 1 < NITER) stage(cur ^ 1, (it + 1) * KVB);

    // ---- QK^T: S[16q][32k] ----
    const char* ktb = (const char*)&Kt[cur][0][0];
    f32x4 s[2];
    s[0] = (f32x4)0.f; s[1] = (f32x4)0.f;
    __builtin_amdgcn_s_setprio(1);
    #pragma unroll
    for (int kk = 0; kk < 8; ++kk) {
      #pragma unroll
      for (int ks = 0; ks < 2; ++ks) {
        const int row = ks*16 + lr;
        short8 kf = *(const short8*)(ktb + row*512 + (((kk*64) + hi*16) ^ swzK(row)));
        s[ks] = __builtin_amdgcn_mfma_f32_16x16x32_bf16(qf[kk], kf, s[ks], 0, 0, 0);
      }
    }
    __builtin_amdgcn_s_setprio(0);

    // ---- online softmax (row = hi*4+r, col = ks*16+lr) ----
    float mx[4];
    #pragma unroll
    for (int r = 0; r < 4; ++r) mx[r] = fmaxf(s[0][r], s[1][r]);
    #pragma unroll
    for (int off = 8; off >= 1; off >>= 1)
      #pragma unroll
      for (int r = 0; r < 4; ++r)
        mx[r] = fmaxf(mx[r], __shfl_xor(mx[r], off, 64));

    #pragma unroll
    for (int r = 0; r < 4; ++r) {
      // conditional rescale: bit-exact skip when max unchanged (sc would be 1.0)
      if (mx[r] > mr[r]) {
        const float sc = __expf(mr[r] - mx[r]);   // first iter: exp(-inf)=0
        mr[r] = mx[r];
        lacc[r] *= sc;
        #pragma unroll
        for (int dt = 0; dt < 16; ++dt) o[dt][r] *= sc;
      }
      const int row = hi*4 + r;
      #pragma unroll
      for (int ks = 0; ks < 2; ++ks) {
        const float p = __expf(s[ks][r] - mr[r]);
        lacc[r] += p;
        *(short*)(plw + row*64 + ((2*(ks*16 + lr)) ^ swzV(row))) = f2bf(p);
      }
    }

    // ---- PV: O[16q][256d] += P[16q][32k] . V[32k][256d] ----
    const char* vtb = (const char*)&Vt[cur][0][0];
    short8 pa = *(const short8*)(plw + lr*64 + ((hi*16) ^ swzV(lr)));
    __builtin_amdgcn_s_setprio(1);
    #pragma unroll
    for (int dt = 0; dt < 16; ++dt) {
      const int d = dt*16 + lr;
      short8 vf = *(const short8*)(vtb + d*64 + ((hi*16) ^ swzV(d)));
      o[dt] = __builtin_amdgcn_mfma_f32_16x16x32_bf16(pa, vf, o[dt], 0, 0, 0);
    }
    __builtin_amdgcn_s_setprio(0);

    __syncthreads();
    cur ^= 1;
  }

  // ---- epilogue: one cross-lane reduce of l, then store ----
  float lsum[4];
  #pragma unroll
  for (int r = 0; r < 4; ++r) lsum[r] = lacc[r];
  #pragma unroll
  for (int off = 8; off >= 1; off >>= 1)
    #pragma unroll
    for (int r = 0; r < 4; ++r)
      lsum[r] += __shfl_xor(lsum[r], off, 64);

  if (KH == 1) {
    float* op = out + ((size_t)b * SQL + q0w) * DIM;
    #pragma unroll
    for (int r = 0; r < 4; ++r) {
      const float inv = 1.0f / lsum[r];
      #pragma unroll
      for (int dt = 0; dt < 16; ++dt)
        op[(size_t)(hi*4 + r) * DIM + dt*16 + lr] = o[dt][r] * inv;
    }
  } else {
    const size_t BS = (size_t)BATCH * SQL;
    float* op = Opart + ((size_t)kh * BS + (size_t)b * SQL + q0w) * DIM;
    #pragma unroll
    for (int r = 0; r < 4; ++r) {
      #pragma unroll
      for (int dt = 0; dt < 16; ++dt)
        op[(size_t)(hi*4 + r) * DIM + dt*16 + lr] = o[dt][r];
      if (lr == 0) {
        float2 e; e.x = mr[r]; e.y = lsum[r];
        ml[kh * BS + (size_t)b * SQL + q0w + hi*4 + r] = e;
      }
    }
  }
}

// ---------- merge the two split-K halves (max-weighted) ----------
__global__ __launch_bounds__(256) void merge_kernel(
    const float* __restrict__ Opart, const float2* __restrict__ ml,
    float* __restrict__ out)
{
  const size_t BS = (size_t)BATCH * SQL;
  const int t  = threadIdx.x;
  const size_t gq = (size_t)blockIdx.x * 4 + (t >> 6);
  const int dl = (t & 63) * 4;
  float2 e0 = ml[gq], e1 = ml[BS + gq];
  const float M  = fmaxf(e0.x, e1.x);
  const float w0 = __expf(e0.x - M);
  const float w1 = __expf(e1.x - M);
  const float inv = 1.0f / (e0.y * w0 + e1.y * w1);
  f32x4 a = *(const f32x4*)(Opart + gq * DIM + dl);
  f32x4 c = *(const f32x4*)(Opart + (BS + gq) * DIM + dl);
  f32x4 r;
  #pragma unroll
  for (int j = 0; j < 4; ++j) r[j] = (a[j] * w0 + c[j] * w1) * inv;
  *(f32x4*)(out + gq * DIM + dl) = r;
}

extern "C" void kernel_launch(void* const* d_in, const int* in_sizes, int n_in,
                              void* d_out, int out_size, void* d_ws, size_t ws_size,
                              hipStream_t stream) {
  const float* query  = (const float*)d_in[0];
  const float* keys   = (const float*)d_in[1];
  const float* values = (const float*)d_in[2];
  const float* Wq = (const float*)d_in[3];
  const float* bq = (const float*)d_in[4];
  const float* Wk = (const float*)d_in[5];
  const float* bk = (const float*)d_in[6];
  const float* Wv = (const float*)d_in[7];
  const float* bv = (const float*)d_in[8];
  float* out = (float*)d_out;

  const size_t elems = (size_t)BATCH * SQL * DIM;          // 8.39M
  const size_t BS    = (size_t)BATCH * SQL;                // 32768
  short* Qb  = (short*)d_ws;
  short* Kb  = Qb + elems;
  short* VtT = Kb + elems;

  const size_t wbytes    = (size_t)3 * DIM * DIM * sizeof(short);
  const size_t need_base = 3 * elems * sizeof(short) + wbytes;
  const size_t need_split = need_base + 2 * elems * sizeof(float) + 2 * BS * sizeof(float2);

  short* Wb;
  bool wb_in_ws = (ws_size >= need_base);
  if (wb_in_ws) Wb = VtT + elems;
  else          Wb = (short*)((char*)d_out + (size_t)out_size * sizeof(float) - wbytes);
  short* Wqb = Wb;
  short* Wkb = Wb + DIM * DIM;
  short* Wvb = Wb + 2 * DIM * DIM;

  dim3 blk(256, 1, 1);
  dim3 blk512(512, 1, 1);
  wcvt_kernel <<<dim3(96, 1, 1),           blk, 0, stream>>>(Wq, Wk, Wv, Wb);
  proj_kernel <<<dim3(BATCH*SQL/32, 1, 1), blk, 0, stream>>>(query,  Wqb, bq, Qb);
  proj_kernel <<<dim3(BATCH*SKL/32, 1, 1), blk, 0, stream>>>(keys,   Wkb, bk, Kb);
  projV_kernel<<<dim3(BATCH*SKL/32, 1, 1), blk, 0, stream>>>(values, Wvb, bv, VtT);

  if (ws_size >= need_split) {
    float*  Opart = (float*)((char*)d_ws + need_base);
    float2* ml    = (float2*)(Opart + 2 * elems);
    attn_kernel<2><<<dim3(512, 1, 1), blk512, 0, stream>>>(Qb, Kb, VtT, out, Opart, ml);
    merge_kernel  <<<dim3(BS/4, 1, 1), blk,    0, stream>>>(Opart, ml, out);
  } else {
    attn_kernel<1><<<dim3(256, 1, 1), blk512, 0, stream>>>(Qb, Kb, VtT, out, nullptr, nullptr);
  }
}

// Round 11
// 317.779 us; speedup vs baseline: 2.1630x; 1.2280x over previous
//
#include <hip/hip_runtime.h>
#include <hip/hip_bf16.h>
#include <math.h>

#define BATCH 8
#define SQL 4096
#define SKL 4096
#define DIM 256
#define KVB 64
#define NIT (SKL / KVB)

typedef __attribute__((ext_vector_type(8))) short short8;
typedef __attribute__((ext_vector_type(4))) float f32x4;
typedef __attribute__((ext_vector_type(4))) float floatx4;

typedef __attribute__((address_space(3))) unsigned int lds_uint;
typedef __attribute__((address_space(1))) unsigned int glob_uint;

__device__ __forceinline__ void gl_lds16(const void* g, void* l) {
  __builtin_amdgcn_global_load_lds((const glob_uint*)g, (lds_uint*)l, 16, 0, 0);
}

__device__ __forceinline__ short f2bf(float f) {
  union { float f; unsigned u; } x; x.f = f;
  unsigned r = x.u + 0x7fffu + ((x.u >> 16) & 1u);
  return (short)(r >> 16);
}

// rows are 512B (Kt) or 128B (Vt/Pl); slot ^= row&7 (bank-derived, 2-way = free)
__device__ __forceinline__ int swz(int row) { return (row & 7) << 4; }

// ---------- W fp32 -> bf16, once ----------
__global__ __launch_bounds__(256) void wcvt_kernel(
    const float* __restrict__ W0, const float* __restrict__ W1,
    const float* __restrict__ W2, short* __restrict__ out)
{
  const int m = blockIdx.x >> 5;
  const int i = ((blockIdx.x & 31) * 256 + threadIdx.x) * 8;
  const float* W = (m == 0) ? W0 : ((m == 1) ? W1 : W2);
  floatx4 a = *(const floatx4*)(W + i);
  floatx4 c = *(const floatx4*)(W + i + 4);
  short8 v;
  #pragma unroll
  for (int j = 0; j < 4; ++j) { v[j] = f2bf(a[j]); v[j+4] = f2bf(c[j]); }
  *(short8*)(out + (size_t)m * DIM * DIM + i) = v;
}

// ---------- projection: 32 m-rows/block; C = X.W^T + b, bf16 row-major out ----------
__global__ __launch_bounds__(256) void proj_kernel(
    const float* __restrict__ X, const short* __restrict__ Wb,
    const float* __restrict__ bias, short* __restrict__ out)
{
  const int lane = threadIdx.x & 63;
  const int wave = threadIdx.x >> 6;
  const int lr = lane & 15, hi = lane >> 4;
  const int m0 = blockIdx.x * 32;
  const int n0 = wave * 64;

  f32x4 acc0[4] = {(f32x4)0.f,(f32x4)0.f,(f32x4)0.f,(f32x4)0.f};
  f32x4 acc1[4] = {(f32x4)0.f,(f32x4)0.f,(f32x4)0.f,(f32x4)0.f};
  const float* xr0 = X + (size_t)(m0 + lr) * DIM;
  const float* xr1 = X + (size_t)(m0 + 16 + lr) * DIM;

  #pragma unroll
  for (int kk = 0; kk < 8; ++kk) {
    const int k8 = kk * 32 + hi * 8;
    floatx4 xa = *(const floatx4*)(xr0 + k8);
    floatx4 xb = *(const floatx4*)(xr0 + k8 + 4);
    floatx4 ya = *(const floatx4*)(xr1 + k8);
    floatx4 yb = *(const floatx4*)(xr1 + k8 + 4);
    short8 a0, a1;
    #pragma unroll
    for (int j = 0; j < 4; ++j) {
      a0[j] = f2bf(xa[j]); a0[j+4] = f2bf(xb[j]);
      a1[j] = f2bf(ya[j]); a1[j+4] = f2bf(yb[j]);
    }
    #pragma unroll
    for (int nb = 0; nb < 4; ++nb) {
      short8 bfr = *(const short8*)(Wb + (size_t)(n0 + nb*16 + lr) * DIM + k8);
      acc0[nb] = __builtin_amdgcn_mfma_f32_16x16x32_bf16(a0, bfr, acc0[nb], 0, 0, 0);
      acc1[nb] = __builtin_amdgcn_mfma_f32_16x16x32_bf16(a1, bfr, acc1[nb], 0, 0, 0);
    }
  }
  #pragma unroll
  for (int nb = 0; nb < 4; ++nb) {
    const int n = n0 + nb*16 + lr;
    const float bv = bias[n];
    #pragma unroll
    for (int r = 0; r < 4; ++r) {
      out[(size_t)(m0 + hi*4 + r) * DIM + n]      = f2bf(acc0[nb][r] + bv);
      out[(size_t)(m0 + 16 + hi*4 + r) * DIM + n] = f2bf(acc1[nb][r] + bv);
    }
  }
}

// ---------- V projection, output TRANSPOSED: outT[b][d][k], 32 rows/block ----------
__global__ __launch_bounds__(256) void projV_kernel(
    const float* __restrict__ X, const short* __restrict__ Wb,
    const float* __restrict__ bias, short* __restrict__ outT)
{
  __shared__ short tile[32][264];
  const int lane = threadIdx.x & 63;
  const int wave = threadIdx.x >> 6;
  const int lr = lane & 15, hi = lane >> 4;
  const int m0 = blockIdx.x * 32;
  const int n0 = wave * 64;

  f32x4 acc0[4] = {(f32x4)0.f,(f32x4)0.f,(f32x4)0.f,(f32x4)0.f};
  f32x4 acc1[4] = {(f32x4)0.f,(f32x4)0.f,(f32x4)0.f,(f32x4)0.f};
  const float* xr0 = X + (size_t)(m0 + lr) * DIM;
  const float* xr1 = X + (size_t)(m0 + 16 + lr) * DIM;

  #pragma unroll
  for (int kk = 0; kk < 8; ++kk) {
    const int k8 = kk * 32 + hi * 8;
    floatx4 xa = *(const floatx4*)(xr0 + k8);
    floatx4 xb = *(const floatx4*)(xr0 + k8 + 4);
    floatx4 ya = *(const floatx4*)(xr1 + k8);
    floatx4 yb = *(const floatx4*)(xr1 + k8 + 4);
    short8 a0, a1;
    #pragma unroll
    for (int j = 0; j < 4; ++j) {
      a0[j] = f2bf(xa[j]); a0[j+4] = f2bf(xb[j]);
      a1[j] = f2bf(ya[j]); a1[j+4] = f2bf(yb[j]);
    }
    #pragma unroll
    for (int nb = 0; nb < 4; ++nb) {
      short8 bfr = *(const short8*)(Wb + (size_t)(n0 + nb*16 + lr) * DIM + k8);
      acc0[nb] = __builtin_amdgcn_mfma_f32_16x16x32_bf16(a0, bfr, acc0[nb], 0, 0, 0);
      acc1[nb] = __builtin_amdgcn_mfma_f32_16x16x32_bf16(a1, bfr, acc1[nb], 0, 0, 0);
    }
  }
  #pragma unroll
  for (int nb = 0; nb < 4; ++nb) {
    const int n = n0 + nb*16 + lr;
    const float bv = bias[n];
    #pragma unroll
    for (int r = 0; r < 4; ++r) {
      tile[hi*4 + r][n]      = f2bf(acc0[nb][r] + bv);
      tile[16 + hi*4 + r][n] = f2bf(acc1[nb][r] + bv);
    }
  }
  __syncthreads();
  const int t = threadIdx.x;
  short8 v0, v1, v2, v3;
  #pragma unroll
  for (int k = 0; k < 8; ++k) {
    v0[k] = tile[k][t]; v1[k] = tile[k+8][t];
    v2[k] = tile[k+16][t]; v3[k] = tile[k+24][t];
  }
  const int b  = m0 >> 12;
  const int k0 = m0 & (SKL - 1);
  short* p = outT + (size_t)b * DIM * SKL + (size_t)t * SKL + k0;
  *(short8*)(p)      = v0;
  *(short8*)(p + 8)  = v1;
  *(short8*)(p + 16) = v2;
  *(short8*)(p + 24) = v3;
}

// ---------- flash attention: 8 waves (512 thr), 16 q/wave, KVB=64, dbuf, exact softmax ----------
__global__ __launch_bounds__(512, 1) void attn_kernel(
    const short* __restrict__ Qb, const short* __restrict__ Kb,
    const short* __restrict__ VtG, float* __restrict__ out)
{
  __shared__ alignas(16) short Kt[2][64][256];   // 64 KB, 512B rows
  __shared__ alignas(16) short Vt[2][256][64];   // 64 KB, 128B rows
  __shared__ alignas(16) short Pl[8][16][64];    // 16 KB per-wave P, 128B rows

  const int tid  = threadIdx.x;
  const int lane = tid & 63;
  const int wave = tid >> 6;                     // 0..7
  const int lr = lane & 15, hi = lane >> 4;

  const int b     = blockIdx.x & 7;     // batch -> XCD pinning (grid=256)
  const int qtile = blockIdx.x >> 3;
  const int q0w   = qtile * 128 + wave * 16;

  const short* Qp = Qb  + ((size_t)b * SQL + q0w) * DIM;
  const short* Kp = Kb  + (size_t)b * SKL * DIM;
  const short* Vp = VtG + (size_t)b * DIM * SKL;

  short8 qf[8];
  #pragma unroll
  for (int kk = 0; kk < 8; ++kk)
    qf[kk] = *(const short8*)(Qp + (size_t)lr * DIM + kk*32 + hi*8);

  f32x4 o[16];
  #pragma unroll
  for (int i = 0; i < 16; ++i) o[i] = (f32x4)0.f;
  float mr[4]   = {-3.0e38f,-3.0e38f,-3.0e38f,-3.0e38f};
  float lacc[4] = {0.f,0.f,0.f,0.f};   // per-lane partial row-sum (this lane's 4 cols)

  auto stage = [&](int buf, int kv) {
    #pragma unroll
    for (int i = 0; i < 4; ++i) {              // K: 64 rows x 512B
      const int row0 = wave*8 + i*2;
      const int row  = row0 + (lane >> 5);
      const int colb = ((lane & 31) * 16) ^ swz(row);
      gl_lds16((const char*)(Kp + (size_t)(kv + row) * DIM) + colb, (void*)&Kt[buf][row0][0]);
    }
    #pragma unroll
    for (int i = 0; i < 4; ++i) {              // V^T: 256 rows x 128B
      const int d0 = wave*32 + i*8;
      const int d  = d0 + (lane >> 3);
      const int colb = ((lane & 7) * 16) ^ swz(d);
      gl_lds16((const char*)(Vp + (size_t)d * SKL + kv) + colb, (void*)&Vt[buf][d0][0]);
    }
  };

  stage(0, 0);
  __syncthreads();
  int cur = 0;

  const char* plw = (const char*)&Pl[wave][0][0];

  for (int it = 0; it < NIT; ++it) {
    if (it + 1 < NIT) stage(cur ^ 1, (it + 1) * KVB);

    // ---- QK^T: S[16q][64k] ----
    const char* ktb = (const char*)&Kt[cur][0][0];
    f32x4 s[4];
    #pragma unroll
    for (int ks = 0; ks < 4; ++ks) s[ks] = (f32x4)0.f;
    __builtin_amdgcn_s_setprio(1);
    #pragma unroll
    for (int kk = 0; kk < 8; ++kk) {
      #pragma unroll
      for (int ks = 0; ks < 4; ++ks) {
        const int row = ks*16 + lr;
        short8 kf = *(const short8*)(ktb + row*512 + (((kk*64) + hi*16) ^ swz(row)));
        s[ks] = __builtin_amdgcn_mfma_f32_16x16x32_bf16(qf[kk], kf, s[ks], 0, 0, 0);
      }
    }
    __builtin_amdgcn_s_setprio(0);

    // ---- EXACT online softmax (row = hi*4+r, col = ks*16+lr): R9-proven numerics ----
    float mx[4];
    #pragma unroll
    for (int r = 0; r < 4; ++r)
      mx[r] = fmaxf(fmaxf(s[0][r], s[1][r]), fmaxf(s[2][r], s[3][r]));
    #pragma unroll
    for (int off = 8; off >= 1; off >>= 1)
      #pragma unroll
      for (int r = 0; r < 4; ++r)
        mx[r] = fmaxf(mx[r], __shfl_xor(mx[r], off, 64));

    #pragma unroll
    for (int r = 0; r < 4; ++r) {
      if (mx[r] > mr[r]) {                       // bit-exact skip of sc==1.0 rescale
        const float sc = __expf(mr[r] - mx[r]);  // first iter: exp(-inf)=0
        mr[r] = mx[r];
        lacc[r] *= sc;
        #pragma unroll
        for (int dt = 0; dt < 16; ++dt) o[dt][r] *= sc;
      }
      const int row = hi*4 + r;
      #pragma unroll
      for (int ks = 0; ks < 4; ++ks) {
        const float p = __expf(s[ks][r] - mr[r]);   // <= 1
        lacc[r] += p;
        *(short*)(plw + row*128 + ((2*(ks*16 + lr)) ^ swz(row))) = f2bf(p);
      }
    }

    // ---- PV: O[16q][256d] += P[16q][64k] . V[64k][256d] ----
    const char* vtb = (const char*)&Vt[cur][0][0];
    short8 pa[2];
    #pragma unroll
    for (int kh = 0; kh < 2; ++kh)
      pa[kh] = *(const short8*)(plw + lr*128 + ((kh*64 + hi*16) ^ swz(lr)));
    __builtin_amdgcn_s_setprio(1);
    #pragma unroll
    for (int dt = 0; dt < 16; ++dt) {
      #pragma unroll
      for (int kh = 0; kh < 2; ++kh) {
        const int d = dt*16 + lr;
        short8 vf = *(const short8*)(vtb + d*128 + ((kh*64 + hi*16) ^ swz(d)));
        o[dt] = __builtin_amdgcn_mfma_f32_16x16x32_bf16(pa[kh], vf, o[dt], 0, 0, 0);
      }
    }
    __builtin_amdgcn_s_setprio(0);

    __syncthreads();
    cur ^= 1;
  }

  // ---- epilogue: one cross-lane reduce of l, normalize, store ----
  float lsum[4];
  #pragma unroll
  for (int r = 0; r < 4; ++r) lsum[r] = lacc[r];
  #pragma unroll
  for (int off = 8; off >= 1; off >>= 1)
    #pragma unroll
    for (int r = 0; r < 4; ++r)
      lsum[r] += __shfl_xor(lsum[r], off, 64);

  float* op = out + ((size_t)b * SQL + q0w) * DIM;
  #pragma unroll
  for (int r = 0; r < 4; ++r) {
    const float inv = 1.0f / lsum[r];
    #pragma unroll
    for (int dt = 0; dt < 16; ++dt)
      op[(size_t)(hi*4 + r) * DIM + dt*16 + lr] = o[dt][r] * inv;
  }
}

extern "C" void kernel_launch(void* const* d_in, const int* in_sizes, int n_in,
                              void* d_out, int out_size, void* d_ws, size_t ws_size,
                              hipStream_t stream) {
  const float* query  = (const float*)d_in[0];
  const float* keys   = (const float*)d_in[1];
  const float* values = (const float*)d_in[2];
  const float* Wq = (const float*)d_in[3];
  const float* bq = (const float*)d_in[4];
  const float* Wk = (const float*)d_in[5];
  const float* bk = (const float*)d_in[6];
  const float* Wv = (const float*)d_in[7];
  const float* bv = (const float*)d_in[8];
  float* out = (float*)d_out;

  const size_t elems = (size_t)BATCH * SQL * DIM;
  short* Qb  = (short*)d_ws;
  short* Kb  = Qb + elems;
  short* VtT = Kb + elems;

  const size_t wbytes    = (size_t)3 * DIM * DIM * sizeof(short);
  const size_t need_base = 3 * elems * sizeof(short) + wbytes;
  short* Wb;
  if (ws_size >= need_base) Wb = VtT + elems;
  else Wb = (short*)((char*)d_out + (size_t)out_size * sizeof(float) - wbytes);
  short* Wqb = Wb;
  short* Wkb = Wb + DIM * DIM;
  short* Wvb = Wb + 2 * DIM * DIM;

  dim3 blk(256, 1, 1);
  dim3 blk512(512, 1, 1);
  wcvt_kernel <<<dim3(96, 1, 1),            blk, 0, stream>>>(Wq, Wk, Wv, Wb);
  proj_kernel <<<dim3(BATCH*SQL/32, 1, 1),  blk, 0, stream>>>(query,  Wqb, bq, Qb);
  proj_kernel <<<dim3(BATCH*SKL/32, 1, 1),  blk, 0, stream>>>(keys,   Wkb, bk, Kb);
  projV_kernel<<<dim3(BATCH*SKL/32, 1, 1),  blk, 0, stream>>>(values, Wvb, bv, VtT);
  attn_kernel <<<dim3(BATCH*SQL/128, 1, 1), blk512, 0, stream>>>(Qb, Kb, VtT, out);
}

// Round 12
// 310.773 us; speedup vs baseline: 2.2117x; 1.0225x over previous
//
#include <hip/hip_runtime.h>
#include <hip/hip_bf16.h>
#include <math.h>

#define BATCH 8
#define SQL 4096
#define SKL 4096
#define DIM 256
#define KVB 64
#define NIT (SKL / KVB)

typedef __attribute__((ext_vector_type(8))) short short8;
typedef __attribute__((ext_vector_type(4))) float f32x4;
typedef __attribute__((ext_vector_type(4))) float floatx4;

typedef __attribute__((address_space(3))) unsigned int lds_uint;
typedef __attribute__((address_space(1))) unsigned int glob_uint;

__device__ __forceinline__ void gl_lds16(const void* g, void* l) {
  __builtin_amdgcn_global_load_lds((const glob_uint*)g, (lds_uint*)l, 16, 0, 0);
}

__device__ __forceinline__ short f2bf(float f) {
  union { float f; unsigned u; } x; x.f = f;
  unsigned r = x.u + 0x7fffu + ((x.u >> 16) & 1u);
  return (short)(r >> 16);
}

// Kt rows 512B / Vt rows 128B: slot ^= row&7 (2-way, free). Pl uses padding instead.
__device__ __forceinline__ int swz(int row) { return (row & 7) << 4; }

// max-reduce across a 16-lane DPP row (our lr-group), pure VALU, bit-exact
__device__ __forceinline__ float dpp_max16(float v) {
  float t;
  t = __int_as_float(__builtin_amdgcn_mov_dpp(__float_as_int(v), 0xB1, 0xF, 0xF, true));  // quad_perm [1,0,3,2] = xor1
  v = fmaxf(v, t);
  t = __int_as_float(__builtin_amdgcn_mov_dpp(__float_as_int(v), 0x4E, 0xF, 0xF, true));  // quad_perm [2,3,0,1] = xor2
  v = fmaxf(v, t);
  t = __int_as_float(__builtin_amdgcn_mov_dpp(__float_as_int(v), 0x124, 0xF, 0xF, true)); // row_ror:4
  v = fmaxf(v, t);
  t = __int_as_float(__builtin_amdgcn_mov_dpp(__float_as_int(v), 0x128, 0xF, 0xF, true)); // row_ror:8
  v = fmaxf(v, t);
  return v;
}

// ---------- W fp32 -> bf16, once ----------
__global__ __launch_bounds__(256) void wcvt_kernel(
    const float* __restrict__ W0, const float* __restrict__ W1,
    const float* __restrict__ W2, short* __restrict__ out)
{
  const int m = blockIdx.x >> 5;
  const int i = ((blockIdx.x & 31) * 256 + threadIdx.x) * 8;
  const float* W = (m == 0) ? W0 : ((m == 1) ? W1 : W2);
  floatx4 a = *(const floatx4*)(W + i);
  floatx4 c = *(const floatx4*)(W + i + 4);
  short8 v;
  #pragma unroll
  for (int j = 0; j < 4; ++j) { v[j] = f2bf(a[j]); v[j+4] = f2bf(c[j]); }
  *(short8*)(out + (size_t)m * DIM * DIM + i) = v;
}

// ---------- projection: 32 m-rows/block; C = X.W^T + b, bf16 row-major out ----------
__global__ __launch_bounds__(256) void proj_kernel(
    const float* __restrict__ X, const short* __restrict__ Wb,
    const float* __restrict__ bias, short* __restrict__ out)
{
  const int lane = threadIdx.x & 63;
  const int wave = threadIdx.x >> 6;
  const int lr = lane & 15, hi = lane >> 4;
  const int m0 = blockIdx.x * 32;
  const int n0 = wave * 64;

  f32x4 acc0[4] = {(f32x4)0.f,(f32x4)0.f,(f32x4)0.f,(f32x4)0.f};
  f32x4 acc1[4] = {(f32x4)0.f,(f32x4)0.f,(f32x4)0.f,(f32x4)0.f};
  const float* xr0 = X + (size_t)(m0 + lr) * DIM;
  const float* xr1 = X + (size_t)(m0 + 16 + lr) * DIM;

  #pragma unroll
  for (int kk = 0; kk < 8; ++kk) {
    const int k8 = kk * 32 + hi * 8;
    floatx4 xa = *(const floatx4*)(xr0 + k8);
    floatx4 xb = *(const floatx4*)(xr0 + k8 + 4);
    floatx4 ya = *(const floatx4*)(xr1 + k8);
    floatx4 yb = *(const floatx4*)(xr1 + k8 + 4);
    short8 a0, a1;
    #pragma unroll
    for (int j = 0; j < 4; ++j) {
      a0[j] = f2bf(xa[j]); a0[j+4] = f2bf(xb[j]);
      a1[j] = f2bf(ya[j]); a1[j+4] = f2bf(yb[j]);
    }
    #pragma unroll
    for (int nb = 0; nb < 4; ++nb) {
      short8 bfr = *(const short8*)(Wb + (size_t)(n0 + nb*16 + lr) * DIM + k8);
      acc0[nb] = __builtin_amdgcn_mfma_f32_16x16x32_bf16(a0, bfr, acc0[nb], 0, 0, 0);
      acc1[nb] = __builtin_amdgcn_mfma_f32_16x16x32_bf16(a1, bfr, acc1[nb], 0, 0, 0);
    }
  }
  #pragma unroll
  for (int nb = 0; nb < 4; ++nb) {
    const int n = n0 + nb*16 + lr;
    const float bv = bias[n];
    #pragma unroll
    for (int r = 0; r < 4; ++r) {
      out[(size_t)(m0 + hi*4 + r) * DIM + n]      = f2bf(acc0[nb][r] + bv);
      out[(size_t)(m0 + 16 + hi*4 + r) * DIM + n] = f2bf(acc1[nb][r] + bv);
    }
  }
}

// ---------- V projection, output TRANSPOSED: outT[b][d][k], 32 rows/block ----------
__global__ __launch_bounds__(256) void projV_kernel(
    const float* __restrict__ X, const short* __restrict__ Wb,
    const float* __restrict__ bias, short* __restrict__ outT)
{
  __shared__ short tile[32][264];
  const int lane = threadIdx.x & 63;
  const int wave = threadIdx.x >> 6;
  const int lr = lane & 15, hi = lane >> 4;
  const int m0 = blockIdx.x * 32;
  const int n0 = wave * 64;

  f32x4 acc0[4] = {(f32x4)0.f,(f32x4)0.f,(f32x4)0.f,(f32x4)0.f};
  f32x4 acc1[4] = {(f32x4)0.f,(f32x4)0.f,(f32x4)0.f,(f32x4)0.f};
  const float* xr0 = X + (size_t)(m0 + lr) * DIM;
  const float* xr1 = X + (size_t)(m0 + 16 + lr) * DIM;

  #pragma unroll
  for (int kk = 0; kk < 8; ++kk) {
    const int k8 = kk * 32 + hi * 8;
    floatx4 xa = *(const floatx4*)(xr0 + k8);
    floatx4 xb = *(const floatx4*)(xr0 + k8 + 4);
    floatx4 ya = *(const floatx4*)(xr1 + k8);
    floatx4 yb = *(const floatx4*)(xr1 + k8 + 4);
    short8 a0, a1;
    #pragma unroll
    for (int j = 0; j < 4; ++j) {
      a0[j] = f2bf(xa[j]); a0[j+4] = f2bf(xb[j]);
      a1[j] = f2bf(ya[j]); a1[j+4] = f2bf(yb[j]);
    }
    #pragma unroll
    for (int nb = 0; nb < 4; ++nb) {
      short8 bfr = *(const short8*)(Wb + (size_t)(n0 + nb*16 + lr) * DIM + k8);
      acc0[nb] = __builtin_amdgcn_mfma_f32_16x16x32_bf16(a0, bfr, acc0[nb], 0, 0, 0);
      acc1[nb] = __builtin_amdgcn_mfma_f32_16x16x32_bf16(a1, bfr, acc1[nb], 0, 0, 0);
    }
  }
  #pragma unroll
  for (int nb = 0; nb < 4; ++nb) {
    const int n = n0 + nb*16 + lr;
    const float bv = bias[n];
    #pragma unroll
    for (int r = 0; r < 4; ++r) {
      tile[hi*4 + r][n]      = f2bf(acc0[nb][r] + bv);
      tile[16 + hi*4 + r][n] = f2bf(acc1[nb][r] + bv);
    }
  }
  __syncthreads();
  const int t = threadIdx.x;
  short8 v0, v1, v2, v3;
  #pragma unroll
  for (int k = 0; k < 8; ++k) {
    v0[k] = tile[k][t]; v1[k] = tile[k+8][t];
    v2[k] = tile[k+16][t]; v3[k] = tile[k+24][t];
  }
  const int b  = m0 >> 12;
  const int k0 = m0 & (SKL - 1);
  short* p = outT + (size_t)b * DIM * SKL + (size_t)t * SKL + k0;
  *(short8*)(p)      = v0;
  *(short8*)(p + 8)  = v1;
  *(short8*)(p + 16) = v2;
  *(short8*)(p + 24) = v3;
}

// ---------- flash attention: 8 waves (512 thr), 16 q/wave, KVB=64, dbuf, exact softmax ----------
__global__ __launch_bounds__(512, 1) void attn_kernel(
    const short* __restrict__ Qb, const short* __restrict__ Kb,
    const short* __restrict__ VtG, float* __restrict__ out)
{
  __shared__ alignas(16) short Kt[2][64][256];   // 64 KB, 512B rows, XOR swz
  __shared__ alignas(16) short Vt[2][256][64];   // 64 KB, 128B rows, XOR swz
  __shared__ alignas(16) short Pl[8][16][72];    // 18 KB, 144B rows (padded, no XOR)

  const int tid  = threadIdx.x;
  const int lane = tid & 63;
  const int wave = tid >> 6;                     // 0..7
  const int lr = lane & 15, hi = lane >> 4;

  const int b     = blockIdx.x & 7;     // batch -> XCD pinning (grid=256)
  const int qtile = blockIdx.x >> 3;
  const int q0w   = qtile * 128 + wave * 16;

  const short* Qp = Qb  + ((size_t)b * SQL + q0w) * DIM;
  const short* Kp = Kb  + (size_t)b * SKL * DIM;
  const short* Vp = VtG + (size_t)b * DIM * SKL;

  short8 qf[8];
  #pragma unroll
  for (int kk = 0; kk < 8; ++kk)
    qf[kk] = *(const short8*)(Qp + (size_t)lr * DIM + kk*32 + hi*8);

  f32x4 o[16];
  #pragma unroll
  for (int i = 0; i < 16; ++i) o[i] = (f32x4)0.f;
  float mr[4]   = {-3.0e38f,-3.0e38f,-3.0e38f,-3.0e38f};
  float lacc[4] = {0.f,0.f,0.f,0.f};   // per-lane partial row-sum (this lane's 4 cols)

  auto stage = [&](int buf, int kv) {
    #pragma unroll
    for (int i = 0; i < 4; ++i) {              // K: 64 rows x 512B
      const int row0 = wave*8 + i*2;
      const int row  = row0 + (lane >> 5);
      const int colb = ((lane & 31) * 16) ^ swz(row);
      gl_lds16((const char*)(Kp + (size_t)(kv + row) * DIM) + colb, (void*)&Kt[buf][row0][0]);
    }
    #pragma unroll
    for (int i = 0; i < 4; ++i) {              // V^T: 256 rows x 128B
      const int d0 = wave*32 + i*8;
      const int d  = d0 + (lane >> 3);
      const int colb = ((lane & 7) * 16) ^ swz(d);
      gl_lds16((const char*)(Vp + (size_t)d * SKL + kv) + colb, (void*)&Vt[buf][d0][0]);
    }
  };

  stage(0, 0);
  __syncthreads();
  int cur = 0;

  const char* plw = (const char*)&Pl[wave][0][0];

  for (int it = 0; it < NIT; ++it) {
    if (it + 1 < NIT) stage(cur ^ 1, (it + 1) * KVB);

    // ---- QK^T: S[16q][64k] ----
    const char* ktb = (const char*)&Kt[cur][0][0];
    f32x4 s[4];
    #pragma unroll
    for (int ks = 0; ks < 4; ++ks) s[ks] = (f32x4)0.f;
    __builtin_amdgcn_s_setprio(1);
    #pragma unroll
    for (int kk = 0; kk < 8; ++kk) {
      #pragma unroll
      for (int ks = 0; ks < 4; ++ks) {
        const int row = ks*16 + lr;
        short8 kf = *(const short8*)(ktb + row*512 + (((kk*64) + hi*16) ^ swz(row)));
        s[ks] = __builtin_amdgcn_mfma_f32_16x16x32_bf16(qf[kk], kf, s[ks], 0, 0, 0);
      }
    }
    __builtin_amdgcn_s_setprio(0);

    // ---- EXACT online softmax (row = hi*4+r, col = ks*16+lr), DPP max-reduce ----
    #pragma unroll
    for (int r = 0; r < 4; ++r) {
      float mx = dpp_max16(fmaxf(fmaxf(s[0][r], s[1][r]), fmaxf(s[2][r], s[3][r])));
      if (mx > mr[r]) {                        // bit-exact skip of sc==1.0 rescale
        const float sc = __expf(mr[r] - mx);   // first iter: exp(-inf)=0
        mr[r] = mx;
        lacc[r] *= sc;
        #pragma unroll
        for (int dt = 0; dt < 16; ++dt) o[dt][r] *= sc;
      }
      const int row = hi*4 + r;
      #pragma unroll
      for (int ks = 0; ks < 4; ++ks) {
        const float p = __expf(s[ks][r] - mr[r]);   // <= 1
        lacc[r] += p;
        *(short*)(plw + row*144 + 2*(ks*16 + lr)) = f2bf(p);
      }
    }

    // ---- PV: O[16q][256d] += P[16q][64k] . V[64k][256d] ----
    const char* vtb = (const char*)&Vt[cur][0][0];
    short8 pa[2];
    #pragma unroll
    for (int kh = 0; kh < 2; ++kh)
      pa[kh] = *(const short8*)(plw + lr*144 + kh*64 + hi*16);
    __builtin_amdgcn_s_setprio(1);
    #pragma unroll
    for (int dt = 0; dt < 16; ++dt) {
      #pragma unroll
      for (int kh = 0; kh < 2; ++kh) {
        const int d = dt*16 + lr;
        short8 vf = *(const short8*)(vtb + d*128 + ((kh*64 + hi*16) ^ swz(d)));
        o[dt] = __builtin_amdgcn_mfma_f32_16x16x32_bf16(pa[kh], vf, o[dt], 0, 0, 0);
      }
    }
    __builtin_amdgcn_s_setprio(0);

    __syncthreads();
    cur ^= 1;
  }

  // ---- epilogue: one cross-lane reduce of l (kept as R11's shfl for bit-identity) ----
  float lsum[4];
  #pragma unroll
  for (int r = 0; r < 4; ++r) lsum[r] = lacc[r];
  #pragma unroll
  for (int off = 8; off >= 1; off >>= 1)
    #pragma unroll
    for (int r = 0; r < 4; ++r)
      lsum[r] += __shfl_xor(lsum[r], off, 64);

  float* op = out + ((size_t)b * SQL + q0w) * DIM;
  #pragma unroll
  for (int r = 0; r < 4; ++r) {
    const float inv = 1.0f / lsum[r];
    #pragma unroll
    for (int dt = 0; dt < 16; ++dt)
      op[(size_t)(hi*4 + r) * DIM + dt*16 + lr] = o[dt][r] * inv;
  }
}

extern "C" void kernel_launch(void* const* d_in, const int* in_sizes, int n_in,
                              void* d_out, int out_size, void* d_ws, size_t ws_size,
                              hipStream_t stream) {
  const float* query  = (const float*)d_in[0];
  const float* keys   = (const float*)d_in[1];
  const float* values = (const float*)d_in[2];
  const float* Wq = (const float*)d_in[3];
  const float* bq = (const float*)d_in[4];
  const float* Wk = (const float*)d_in[5];
  const float* bk = (const float*)d_in[6];
  const float* Wv = (const float*)d_in[7];
  const float* bv = (const float*)d_in[8];
  float* out = (float*)d_out;

  const size_t elems = (size_t)BATCH * SQL * DIM;
  short* Qb  = (short*)d_ws;
  short* Kb  = Qb + elems;
  short* VtT = Kb + elems;

  const size_t wbytes    = (size_t)3 * DIM * DIM * sizeof(short);
  const size_t need_base = 3 * elems * sizeof(short) + wbytes;
  short* Wb;
  if (ws_size >= need_base) Wb = VtT + elems;
  else Wb = (short*)((char*)d_out + (size_t)out_size * sizeof(float) - wbytes);
  short* Wqb = Wb;
  short* Wkb = Wb + DIM * DIM;
  short* Wvb = Wb + 2 * DIM * DIM;

  dim3 blk(256, 1, 1);
  dim3 blk512(512, 1, 1);
  wcvt_kernel <<<dim3(96, 1, 1),            blk, 0, stream>>>(Wq, Wk, Wv, Wb);
  proj_kernel <<<dim3(BATCH*SQL/32, 1, 1),  blk, 0, stream>>>(query,  Wqb, bq, Qb);
  proj_kernel <<<dim3(BATCH*SKL/32, 1, 1),  blk, 0, stream>>>(keys,   Wkb, bk, Kb);
  projV_kernel<<<dim3(BATCH*SKL/32, 1, 1),  blk, 0, stream>>>(values, Wvb, bv, VtT);
  attn_kernel <<<dim3(BATCH*SQL/128, 1, 1), blk512, 0, stream>>>(Qb, Kb, VtT, out);
}